// Round 4
// baseline (647.200 us; speedup 1.0000x reference)
//
#include <hip/hip_runtime.h>
#include <hip/hip_bf16.h>
#include <math.h>

typedef __attribute__((ext_vector_type(8))) short short8;      // 8 bf16 (4 VGPRs)
typedef __attribute__((ext_vector_type(4))) float f32x4;       // MFMA acc
typedef __attribute__((ext_vector_type(4))) unsigned short us4;

#define MFMA16(a,b,c) __builtin_amdgcn_mfma_f32_16x16x32_bf16((a),(b),(c),0,0,0)

// ---------------- workspace layout (bytes) ----------------
#define OFF_W1CAT   0u         // bf16 [9][128][256]  (A0,A1,B0,B1,Ceff0,Ceff1,D0,D1,S)
#define OFF_W2CAT   589824u    // bf16 [7][128][128]  (A0,A1,B0,B1,D0,D1,S)
#define OFF_B1      950272u    // f32 [9][128]
#define OFF_B2      954880u    // f32 [7][128]
#define OFF_LNG     958464u    // f32 [3][128] (D0,D1,S gains)
#define OFF_LNB     960000u    // f32 [3][128]
#define OFF_BSC     961536u    // f32 [2][128] B_g
#define OFF_BBI     962560u    // f32 [2][128] B_be
#define OFF_USAGE   963584u    // f32 [8]
#define OFF_W8      963712u    // f32 [32768][8]
#define OFF_W1T     2012288u   // f32 [257][128]  gate W1 transposed

__device__ __forceinline__ unsigned short f2bf(float f) {
  union { float f; unsigned u; } v; v.f = f;
  return (unsigned short)((v.u + 0x7fffu + ((v.u >> 16) & 1u)) >> 16);
}

// ============== prep: pack weights to bf16, fold conv into Weff ==============
__global__ __launch_bounds__(256) void prep_kernel(
    const float* __restrict__ A_W1, const float* __restrict__ A_b1,
    const float* __restrict__ A_W2, const float* __restrict__ A_b2,
    const float* __restrict__ B_W1, const float* __restrict__ B_b1,
    const float* __restrict__ B_g,  const float* __restrict__ B_be,
    const float* __restrict__ B_W2, const float* __restrict__ B_b2,
    const float* __restrict__ C_cw, const float* __restrict__ C_cb,
    const float* __restrict__ C_W,  const float* __restrict__ C_b,
    const float* __restrict__ D_W1, const float* __restrict__ D_b1,
    const float* __restrict__ D_g,  const float* __restrict__ D_be,
    const float* __restrict__ D_W2, const float* __restrict__ D_b2,
    const float* __restrict__ S_W1, const float* __restrict__ S_b1,
    const float* __restrict__ S_g,  const float* __restrict__ S_be,
    const float* __restrict__ S_W2, const float* __restrict__ S_b2,
    const float* __restrict__ G_W1,
    unsigned short* __restrict__ W1cat, unsigned short* __restrict__ W2cat,
    float* __restrict__ W1T,
    float* __restrict__ b1cat, float* __restrict__ b2cat,
    float* __restrict__ lng, float* __restrict__ lnb,
    float* __restrict__ bsc, float* __restrict__ bbi,
    float* __restrict__ usage)
{
  int tid = blockIdx.x * 256 + threadIdx.x;
  if (tid < 294912) {                       // W1cat
    int g = tid / 32768, rem = tid % 32768;
    float v;
    if (g < 2)      v = A_W1[tid];
    else if (g < 4) v = B_W1[rem + (g - 2) * 32768];
    else if (g < 6) {                       // Weff = conv folded into C_W
      int e = g - 4, p = rem / 256, i = rem % 256;
      v = 0.f;
      for (int c = 0; c < 4; ++c)
        for (int j = 0; j < 3; ++j) {
          int h = i + 1 - j;
          if (h >= 0 && h < 256)
            v += C_cw[e*12 + c*3 + j] * C_W[e*131072 + p*1024 + c*256 + h];
        }
    }
    else if (g < 8) v = D_W1[rem + (g - 6) * 32768];
    else            v = S_W1[rem];
    W1cat[tid] = f2bf(v);
    return;
  }
  tid -= 294912;
  if (tid < 114688) {                       // W2cat
    int g = tid / 16384, rem = tid % 16384;
    float v;
    if (g < 2)      v = A_W2[tid];
    else if (g < 4) v = B_W2[rem + (g - 2) * 16384];
    else if (g < 6) v = D_W2[rem + (g - 4) * 16384];
    else            v = S_W2[rem];
    W2cat[tid] = f2bf(v);
    return;
  }
  tid -= 114688;
  if (tid < 32896) {                        // W1T[k][o] = G_W1[o][k]
    int k = tid / 128, o = tid % 128;
    W1T[tid] = G_W1[o * 257 + k];
    return;
  }
  tid -= 32896;
  if (tid < 1152) {                         // b1cat (incl. folded conv bias)
    int g = tid / 128, p = tid % 128;
    float v;
    if (g < 2)      v = A_b1[tid];
    else if (g < 4) v = B_b1[p + (g - 2) * 128];
    else if (g < 6) {
      int e = g - 4;
      v = C_b[e * 128 + p];
      for (int c = 0; c < 4; ++c) {
        float s = 0.f;
        for (int h = 0; h < 256; ++h) s += C_W[e*131072 + p*1024 + c*256 + h];
        v += C_cb[e * 4 + c] * s;
      }
    }
    else if (g < 8) v = D_b1[p + (g - 6) * 128];
    else            v = S_b1[p];
    b1cat[tid] = v;
    return;
  }
  tid -= 1152;
  if (tid < 896) {                          // b2cat
    int g = tid / 128, p = tid % 128;
    float v;
    if (g < 2)      v = A_b2[tid];
    else if (g < 4) v = B_b2[p + (g - 2) * 128];
    else if (g < 6) v = D_b2[p + (g - 4) * 128];
    else            v = S_b2[p];
    b2cat[tid] = v;
    return;
  }
  tid -= 896;
  if (tid < 768) {                          // LN gains/biases (D0,D1,S)
    if (tid < 384) {
      int j = tid / 128, p = tid % 128;
      lng[tid] = (j < 2) ? D_g[tid] : S_g[p];
    } else {
      int q = tid - 384; int j = q / 128, p = q % 128;
      lnb[q] = (j < 2) ? D_be[q] : S_be[p];
    }
    return;
  }
  tid -= 768;
  if (tid < 512) {                          // B scale/shift
    if (tid < 256) bsc[tid] = B_g[tid];
    else           bbi[tid - 256] = B_be[tid - 256];
    return;
  }
  tid -= 512;
  if (tid < 8) usage[tid] = 0.f;
}

// ============== gate: emulate np/BLAS f32 sequential-k FMA exactly ==============
// Block = 4 waves / 128 tokens. Wave (grp,half): lane = token (64 of them),
// computes o in [half*64, half*64+64) via sequential-k fmaf chains (k=0..255
// then mod column), + b1 (f32 add), tanh (f64, round to f32) -> LDS.
// Layer 2: 32 lanes/wave, one token each: sequential-o fmaf chains, + b2,
// /0.7f (f32 div), clip, strict lowest-index top-4, f32 softmax.
__global__ __launch_bounds__(256) void gate_np_kernel(
    const float* __restrict__ x, const int* __restrict__ modality,
    const float* __restrict__ W1T, const float* __restrict__ G_b1,
    const float* __restrict__ G_W2, const float* __restrict__ G_b2,
    float* __restrict__ w8full, float* __restrict__ usage)
{
  __shared__ float ghs[128][129];
  const int wv = threadIdx.x >> 6, lane = threadIdx.x & 63;
  const int grp = wv >> 1;
  const int hh = __builtin_amdgcn_readfirstlane(wv & 1);   // o-half, SGPR
  const int tl = grp * 64 + lane;                          // block-local token
  const int token = blockIdx.x * 128 + tl;

  float acc[64];
#pragma unroll
  for (int j = 0; j < 64; ++j) acc[j] = 0.f;

  const float* xr = x + (size_t)token * 256;
  const float* wbase = W1T + hh * 64;
#pragma unroll 2
  for (int k = 0; k < 256; ++k) {
    float xv = xr[k];
    const float* wk = wbase + k * 128;
#pragma unroll
    for (int j = 0; j < 64; ++j) acc[j] = fmaf(xv, wk[j], acc[j]);
  }
  {
    float xv = (float)modality[token];                     // k = 256 (mod col)
    const float* wk = wbase + 256 * 128;
#pragma unroll
    for (int j = 0; j < 64; ++j) acc[j] = fmaf(xv, wk[j], acc[j]);
  }
#pragma unroll
  for (int j = 0; j < 64; ++j) {
    int o = hh * 64 + j;
    float s = acc[j] + G_b1[o];                            // separate f32 add
    ghs[tl][o] = (float)tanh((double)s);                   // CR tanh -> f32
  }
  __syncthreads();

  float uw[8];
#pragma unroll
  for (int e = 0; e < 8; ++e) uw[e] = 0.f;

  if (lane < 32) {
    int tl2 = wv * 32 + lane;
    int tok2 = blockIdx.x * 128 + tl2;
    float lg[8];
#pragma unroll
    for (int e = 0; e < 8; ++e) lg[e] = 0.f;
    for (int o = 0; o < 128; ++o) {
      float g = ghs[tl2][o];
#pragma unroll
      for (int e = 0; e < 8; ++e) lg[e] = fmaf(g, G_W2[e * 128 + o], lg[e]);
    }
    float v[8];
#pragma unroll
    for (int e = 0; e < 8; ++e) {
      float s = (lg[e] + G_b2[e]) / 0.7f;                  // f32 div, not *inv
      v[e] = fminf(fmaxf(s, -10.f), 10.f);
    }
    float tv[4]; int ti[4]; unsigned msk = 0;
    for (int kk = 0; kk < 4; ++kk) {                       // ties -> lowest idx
      float best = -1e30f; int bi = 0;
      for (int e = 0; e < 8; ++e)
        if (!((msk >> e) & 1u) && v[e] > best) { best = v[e]; bi = e; }
      tv[kk] = best; ti[kk] = bi; msk |= 1u << bi;
    }
    float mx = tv[0], den = 0.f, wk4[4];
#pragma unroll
    for (int kk = 0; kk < 4; ++kk) { wk4[kk] = expf(tv[kk] - mx); den += wk4[kk]; }
#pragma unroll
    for (int e = 0; e < 8; ++e) {
      float val = 0.f;
#pragma unroll
      for (int kk = 0; kk < 4; ++kk) if (ti[kk] == e) val = wk4[kk] / den;
      w8full[(size_t)tok2 * 8 + e] = val;
    }
    float dall = 0.f, pe[8];
#pragma unroll
    for (int e = 0; e < 8; ++e) { pe[e] = expf(v[e] - mx); dall += pe[e]; }
#pragma unroll
    for (int e = 0; e < 8; ++e) uw[e] = pe[e] / dall;
  }
  for (int m = 1; m <= 32; m <<= 1)
#pragma unroll
    for (int e = 0; e < 8; ++e) uw[e] += __shfl_xor(uw[e], m);
  if (lane == 0)
    for (int e = 0; e < 8; ++e) atomicAdd(usage + e, uw[e]);
}

// ============== fused experts + shared + combine ==============
__global__ __launch_bounds__(256) void moe_kernel(
    const float* __restrict__ x,
    const unsigned short* __restrict__ W1cat, const unsigned short* __restrict__ W2cat,
    const float* __restrict__ b1cat, const float* __restrict__ b2cat,
    const float* __restrict__ lng, const float* __restrict__ lnb,
    const float* __restrict__ bsc, const float* __restrict__ bbi,
    const float* __restrict__ w8full, float* __restrict__ out)
{
  __shared__ unsigned char smem[4 * 12288];
  const int w = threadIdx.x >> 6, lane = threadIdx.x & 63;
  const int l15 = lane & 15, l4 = lane >> 4;
  unsigned char* XS = smem + w * 12288;     // bf16 [16][256] swizzled (per wave)
  unsigned char* HS = XS + 8192;            // bf16 [16][128] swizzled (per wave)
  const int tb = blockIdx.x * 64 + w * 16;

  for (int r = 0; r < 16; ++r) {
    const float4 v = *(const float4*)(x + (size_t)(tb + r) * 256 + lane * 4);
    float vv[4] = {v.x, v.y, v.z, v.w};
    us4 hi;
#pragma unroll
    for (int j = 0; j < 4; ++j) hi[j] = f2bf(vv[j]);
    int addr = r * 512 + ((((lane >> 1) ^ (r & 7)) << 4) | ((lane & 1) << 3));
    *(us4*)(XS + addr) = hi;
  }
  __syncthreads();

  f32x4 zero = {0.f, 0.f, 0.f, 0.f};
  f32x4 pacc[8];
#pragma unroll
  for (int nt = 0; nt < 8; ++nt) pacc[nt] = zero;
  const float RS = 1.0f / sqrtf(1.0f + 1e-5f);

  for (int g = 0; g < 9; ++g) {
    const unsigned short* W1 = W1cat + g * 32768;
    f32x4 acc[8];
#pragma unroll
    for (int nt = 0; nt < 8; ++nt) acc[nt] = zero;
    for (int ks = 0; ks < 8; ++ks) {
      int ar = l15 * 512 + ((((ks * 4 + l4) ^ (l15 & 7)) << 4));
      short8 a = *(const short8*)(XS + ar);
#pragma unroll
      for (int nt = 0; nt < 8; ++nt) {
        const short8 b = *(const short8*)(W1 + (nt * 16 + l15) * 256 + ks * 32 + l4 * 8);
        acc[nt] = MFMA16(a, b, acc[nt]);
      }
    }
    const float* b1 = b1cat + g * 128;
    const int type = (g < 2) ? 0 : (g < 4) ? 1 : (g < 6) ? 2 : (g < 8) ? 3 : 4;

    if (type == 2) {                        // C: gelu(exact) -> weighted combine
#pragma unroll
      for (int r = 0; r < 4; ++r) {
        float wv = w8full[(size_t)(tb + l4 * 4 + r) * 8 + g];
#pragma unroll
        for (int nt = 0; nt < 8; ++nt) {
          float h = acc[nt][r] + b1[nt * 16 + l15];
          h = 0.5f * h * (1.0f + erff(h * 0.70710678118654752f));
          pacc[nt][r] += wv * h;
        }
      }
      continue;
    }
    // activation
#pragma unroll
    for (int r = 0; r < 4; ++r) {
#pragma unroll
      for (int nt = 0; nt < 8; ++nt) {
        float h = acc[nt][r] + b1[nt * 16 + l15];
        if (type == 0)      h = fmaxf(h, 0.f);
        else if (type == 1) {
          int col = (g - 2) * 128 + nt * 16 + l15;
          h = tanhf(h) * RS * bsc[col] + bbi[col];
        }
        else if (type == 3) h = h / (1.f + expf(-h));   // silu
        else                h = fmaxf(h, 0.f);          // S: relu
        acc[nt][r] = h;
      }
    }
    if (type >= 3) {                        // layernorm via lane-group shuffles
      int li = (type == 3) ? (g - 6) : 2;
#pragma unroll
      for (int r = 0; r < 4; ++r) {
        float s1 = 0.f, s2 = 0.f;
#pragma unroll
        for (int nt = 0; nt < 8; ++nt) { float h = acc[nt][r]; s1 += h; s2 += h * h; }
        for (int m = 1; m <= 8; m <<= 1) { s1 += __shfl_xor(s1, m); s2 += __shfl_xor(s2, m); }
        float mu = s1 * (1.f / 128.f);
        float var = s2 * (1.f / 128.f) - mu * mu;
        float sc = 1.f / sqrtf(var + 1e-5f);
#pragma unroll
        for (int nt = 0; nt < 8; ++nt) {
          int col = nt * 16 + l15;
          acc[nt][r] = (acc[nt][r] - mu) * sc * lng[li * 128 + col] + lnb[li * 128 + col];
        }
      }
    }
    // write h tile (bf16, swizzled)
#pragma unroll
    for (int r = 0; r < 4; ++r) {
      int row = l4 * 4 + r;
#pragma unroll
      for (int nt = 0; nt < 8; ++nt) {
        int bytecol = (nt * 16 + l15) * 2;
        int addr = row * 256 + ((((bytecol >> 4) ^ (row & 7)) << 4) | (bytecol & 15));
        *(unsigned short*)(HS + addr) = f2bf(acc[nt][r]);
      }
    }
    __syncthreads();
    // GEMM2: h(16x128) @ W2^T
    const int g2 = (g < 4) ? g : (g - 2);
    const unsigned short* W2 = W2cat + g2 * 16384;
    f32x4 acc2[8];
#pragma unroll
    for (int nt = 0; nt < 8; ++nt) acc2[nt] = zero;
    for (int ks = 0; ks < 4; ++ks) {
      int ar = l15 * 256 + ((((ks * 4 + l4) ^ (l15 & 7)) << 4));
      short8 a = *(const short8*)(HS + ar);
#pragma unroll
      for (int nt = 0; nt < 8; ++nt) {
        const short8 b = *(const short8*)(W2 + (nt * 16 + l15) * 128 + ks * 32 + l4 * 8);
        acc2[nt] = MFMA16(a, b, acc2[nt]);
      }
    }
    const float* b2 = b2cat + g2 * 128;
    if (g == 8) {                           // shared output
#pragma unroll
      for (int r = 0; r < 4; ++r) {
        int token = tb + l4 * 4 + r;
#pragma unroll
        for (int nt = 0; nt < 8; ++nt)
          out[(size_t)token * 128 + nt * 16 + l15] = acc2[nt][r] + b2[nt * 16 + l15];
      }
    } else {                                // weighted combine into private
#pragma unroll
      for (int r = 0; r < 4; ++r) {
        float wv = w8full[(size_t)(tb + l4 * 4 + r) * 8 + g];
#pragma unroll
        for (int nt = 0; nt < 8; ++nt)
          pacc[nt][r] += wv * (acc2[nt][r] + b2[nt * 16 + l15]);
      }
    }
  }
#pragma unroll
  for (int r = 0; r < 4; ++r) {
    int token = tb + l4 * 4 + r;
#pragma unroll
    for (int nt = 0; nt < 8; ++nt)
      out[4194304 + (size_t)token * 128 + nt * 16 + l15] = pacc[nt][r];
  }
}

// ============== aux scalar ==============
__global__ void aux_kernel(const float* __restrict__ usage, float* __restrict__ out) {
  if (threadIdx.x == 0 && blockIdx.x == 0) {
    float a = 0.f;
    for (int e = 0; e < 8; ++e) {
      float u = usage[e] * (1.0f / 32768.0f);
      a += 0.125f * (logf(0.125f) - logf(u + 1e-10f));
    }
    out[8388608] = a * 0.125f;
  }
}

extern "C" void kernel_launch(void* const* d_in, const int* in_sizes, int n_in,
                              void* d_out, int out_size, void* d_ws, size_t ws_size,
                              hipStream_t stream) {
  (void)in_sizes; (void)n_in; (void)out_size; (void)ws_size;
  const float* x    = (const float*)d_in[0];
  const int*   mod  = (const int*)d_in[1];
  const float* A_W1 = (const float*)d_in[2];
  const float* A_b1 = (const float*)d_in[3];
  const float* A_W2 = (const float*)d_in[4];
  const float* A_b2 = (const float*)d_in[5];
  const float* B_W1 = (const float*)d_in[6];
  const float* B_b1 = (const float*)d_in[7];
  const float* B_g  = (const float*)d_in[8];
  const float* B_be = (const float*)d_in[9];
  const float* B_W2 = (const float*)d_in[10];
  const float* B_b2 = (const float*)d_in[11];
  const float* C_cw = (const float*)d_in[12];
  const float* C_cb = (const float*)d_in[13];
  const float* C_W  = (const float*)d_in[14];
  const float* C_b  = (const float*)d_in[15];
  const float* D_W1 = (const float*)d_in[16];
  const float* D_b1 = (const float*)d_in[17];
  const float* D_g  = (const float*)d_in[18];
  const float* D_be = (const float*)d_in[19];
  const float* D_W2 = (const float*)d_in[20];
  const float* D_b2 = (const float*)d_in[21];
  const float* S_W1 = (const float*)d_in[22];
  const float* S_b1 = (const float*)d_in[23];
  const float* S_g  = (const float*)d_in[24];
  const float* S_be = (const float*)d_in[25];
  const float* S_W2 = (const float*)d_in[26];
  const float* S_b2 = (const float*)d_in[27];
  const float* G_W1 = (const float*)d_in[28];
  const float* G_b1 = (const float*)d_in[29];
  const float* G_W2 = (const float*)d_in[30];
  const float* G_b2 = (const float*)d_in[31];

  char* ws = (char*)d_ws;
  unsigned short* W1cat = (unsigned short*)(ws + OFF_W1CAT);
  unsigned short* W2cat = (unsigned short*)(ws + OFF_W2CAT);
  float* W1T    = (float*)(ws + OFF_W1T);
  float* b1cat  = (float*)(ws + OFF_B1);
  float* b2cat  = (float*)(ws + OFF_B2);
  float* lng    = (float*)(ws + OFF_LNG);
  float* lnb    = (float*)(ws + OFF_LNB);
  float* bsc    = (float*)(ws + OFF_BSC);
  float* bbi    = (float*)(ws + OFF_BBI);
  float* usage  = (float*)(ws + OFF_USAGE);
  float* w8full = (float*)(ws + OFF_W8);
  float* out    = (float*)d_out;

  prep_kernel<<<1742, 256, 0, stream>>>(A_W1, A_b1, A_W2, A_b2, B_W1, B_b1, B_g, B_be,
      B_W2, B_b2, C_cw, C_cb, C_W, C_b, D_W1, D_b1, D_g, D_be, D_W2, D_b2,
      S_W1, S_b1, S_g, S_be, S_W2, S_b2, G_W1,
      W1cat, W2cat, W1T, b1cat, b2cat, lng, lnb, bsc, bbi, usage);
  gate_np_kernel<<<256, 256, 0, stream>>>(x, mod, W1T, G_b1, G_W2, G_b2,
      w8full, usage);
  moe_kernel<<<512, 256, 0, stream>>>(x, W1cat, W2cat, b1cat, b2cat, lng, lnb,
      bsc, bbi, w8full, out);
  aux_kernel<<<1, 64, 0, stream>>>(usage, out);
}

// Round 5
// 482.494 us; speedup vs baseline: 1.3414x; 1.3414x over previous
//
#include <hip/hip_runtime.h>
#include <hip/hip_bf16.h>
#include <math.h>

typedef __attribute__((ext_vector_type(8))) short short8;      // 8 bf16 (4 VGPRs)
typedef __attribute__((ext_vector_type(4))) float f32x4;       // MFMA acc
typedef __attribute__((ext_vector_type(4))) unsigned short us4;

#define MFMA16(a,b,c) __builtin_amdgcn_mfma_f32_16x16x32_bf16((a),(b),(c),0,0,0)

// ---------------- workspace layout (bytes) ----------------
#define OFF_W1CAT   0u         // bf16 [9][128][256]  (A0,A1,B0,B1,Ceff0,Ceff1,D0,D1,S)
#define OFF_W2CAT   589824u    // bf16 [7][128][128]  (A0,A1,B0,B1,D0,D1,S)
#define OFF_B1      950272u    // f32 [9][128]
#define OFF_B2      954880u    // f32 [7][128]
#define OFF_LNG     958464u    // f32 [3][128] (D0,D1,S gains)
#define OFF_LNB     960000u    // f32 [3][128]
#define OFF_BSC     961536u    // f32 [2][128] B_g
#define OFF_BBI     962560u    // f32 [2][128] B_be
#define OFF_USAGE   963584u    // f32 [8]
#define OFF_W8      963712u    // f32 [32768][8]
#define OFF_W1T     2012288u   // f32 [257][128]  gate W1 transposed

__device__ __forceinline__ unsigned short f2bf(float f) {
  union { float f; unsigned u; } v; v.f = f;
  return (unsigned short)((v.u + 0x7fffu + ((v.u >> 16) & 1u)) >> 16);
}

// ============== prep: pack weights to bf16, fold conv into Weff ==============
__global__ __launch_bounds__(256) void prep_kernel(
    const float* __restrict__ A_W1, const float* __restrict__ A_b1,
    const float* __restrict__ A_W2, const float* __restrict__ A_b2,
    const float* __restrict__ B_W1, const float* __restrict__ B_b1,
    const float* __restrict__ B_g,  const float* __restrict__ B_be,
    const float* __restrict__ B_W2, const float* __restrict__ B_b2,
    const float* __restrict__ C_cw, const float* __restrict__ C_cb,
    const float* __restrict__ C_W,  const float* __restrict__ C_b,
    const float* __restrict__ D_W1, const float* __restrict__ D_b1,
    const float* __restrict__ D_g,  const float* __restrict__ D_be,
    const float* __restrict__ D_W2, const float* __restrict__ D_b2,
    const float* __restrict__ S_W1, const float* __restrict__ S_b1,
    const float* __restrict__ S_g,  const float* __restrict__ S_be,
    const float* __restrict__ S_W2, const float* __restrict__ S_b2,
    const float* __restrict__ G_W1,
    unsigned short* __restrict__ W1cat, unsigned short* __restrict__ W2cat,
    float* __restrict__ W1T,
    float* __restrict__ b1cat, float* __restrict__ b2cat,
    float* __restrict__ lng, float* __restrict__ lnb,
    float* __restrict__ bsc, float* __restrict__ bbi,
    float* __restrict__ usage)
{
  int tid = blockIdx.x * 256 + threadIdx.x;
  if (tid < 294912) {                       // W1cat
    int g = tid / 32768, rem = tid % 32768;
    float v;
    if (g < 2)      v = A_W1[tid];
    else if (g < 4) v = B_W1[rem + (g - 2) * 32768];
    else if (g < 6) {                       // Weff = conv folded into C_W
      int e = g - 4, p = rem / 256, i = rem % 256;
      v = 0.f;
      for (int c = 0; c < 4; ++c)
        for (int j = 0; j < 3; ++j) {
          int h = i + 1 - j;
          if (h >= 0 && h < 256)
            v += C_cw[e*12 + c*3 + j] * C_W[e*131072 + p*1024 + c*256 + h];
        }
    }
    else if (g < 8) v = D_W1[rem + (g - 6) * 32768];
    else            v = S_W1[rem];
    W1cat[tid] = f2bf(v);
    return;
  }
  tid -= 294912;
  if (tid < 114688) {                       // W2cat
    int g = tid / 16384, rem = tid % 16384;
    float v;
    if (g < 2)      v = A_W2[tid];
    else if (g < 4) v = B_W2[rem + (g - 2) * 16384];
    else if (g < 6) v = D_W2[rem + (g - 4) * 16384];
    else            v = S_W2[rem];
    W2cat[tid] = f2bf(v);
    return;
  }
  tid -= 114688;
  if (tid < 32896) {                        // W1T[k][o] = G_W1[o][k]
    int k = tid / 128, o = tid % 128;
    W1T[tid] = G_W1[o * 257 + k];
    return;
  }
  tid -= 32896;
  if (tid < 1152) {                         // b1cat (incl. folded conv bias)
    int g = tid / 128, p = tid % 128;
    float v;
    if (g < 2)      v = A_b1[tid];
    else if (g < 4) v = B_b1[p + (g - 2) * 128];
    else if (g < 6) {
      int e = g - 4;
      v = C_b[e * 128 + p];
      for (int c = 0; c < 4; ++c) {
        float s = 0.f;
        for (int h = 0; h < 256; ++h) s += C_W[e*131072 + p*1024 + c*256 + h];
        v += C_cb[e * 4 + c] * s;
      }
    }
    else if (g < 8) v = D_b1[p + (g - 6) * 128];
    else            v = S_b1[p];
    b1cat[tid] = v;
    return;
  }
  tid -= 1152;
  if (tid < 896) {                          // b2cat
    int g = tid / 128, p = tid % 128;
    float v;
    if (g < 2)      v = A_b2[tid];
    else if (g < 4) v = B_b2[p + (g - 2) * 128];
    else if (g < 6) v = D_b2[p + (g - 4) * 128];
    else            v = S_b2[p];
    b2cat[tid] = v;
    return;
  }
  tid -= 896;
  if (tid < 768) {                          // LN gains/biases (D0,D1,S)
    if (tid < 384) {
      int j = tid / 128, p = tid % 128;
      lng[tid] = (j < 2) ? D_g[tid] : S_g[p];
    } else {
      int q = tid - 384; int j = q / 128, p = q % 128;
      lnb[q] = (j < 2) ? D_be[q] : S_be[p];
    }
    return;
  }
  tid -= 768;
  if (tid < 512) {                          // B scale/shift
    if (tid < 256) bsc[tid] = B_g[tid];
    else           bbi[tid - 256] = B_be[tid - 256];
    return;
  }
  tid -= 512;
  if (tid < 8) usage[tid] = 0.f;
}

// ============== gate v2: o-on-lanes, token-in-registers; exact np FMA order ==============
// Block = 256 thr = 4 waves, 32 tokens. Wave (tg,hh): tokens [tg*16,+16),
// o = hh*64+lane. 16 independent sequential-k FMA chains per lane.
// x reads are wave-uniform (scalar); W1T reads coalesced.
__global__ __launch_bounds__(256) void gate_np_kernel(
    const float* __restrict__ x, const int* __restrict__ modality,
    const float* __restrict__ W1T, const float* __restrict__ G_b1,
    const float* __restrict__ G_W2, const float* __restrict__ G_b2,
    float* __restrict__ w8full, float* __restrict__ usage)
{
  __shared__ float ghs[32][129];
  __shared__ float lgs[32][9];
  __shared__ float ws2[8][132];
  const int wv = threadIdx.x >> 6, lane = threadIdx.x & 63;
  const int tg = wv >> 1, hh = wv & 1;
  const int o = hh * 64 + lane;
  const int tbase = __builtin_amdgcn_readfirstlane(blockIdx.x * 32 + tg * 16);

  for (int i = threadIdx.x; i < 1024; i += 256)
    ws2[i >> 7][i & 127] = G_W2[i];

  float acc[16];
#pragma unroll
  for (int t = 0; t < 16; ++t) acc[t] = 0.f;

  const float* xb = x + (size_t)tbase * 256;
#pragma unroll 4
  for (int k = 0; k < 256; ++k) {
    float wk = W1T[k * 128 + o];
#pragma unroll
    for (int t = 0; t < 16; ++t)
      acc[t] = fmaf(xb[t * 256 + k], wk, acc[t]);
  }
  {
    float wm = W1T[256 * 128 + o];
#pragma unroll
    for (int t = 0; t < 16; ++t)
      acc[t] = fmaf((float)modality[tbase + t], wm, acc[t]);
  }
  float bo = G_b1[o];
#pragma unroll
  for (int t = 0; t < 16; ++t)
    ghs[tg * 16 + t][o] = (float)tanh((double)(acc[t] + bo));   // CR tanh -> f32
  __syncthreads();

  // layer 2: thread = (token t2, expert e2); sequential-o fmaf chain
  {
    const int t2 = threadIdx.x >> 3, e2 = threadIdx.x & 7;
    float lg = 0.f;
    for (int o2 = 0; o2 < 128; ++o2)
      lg = fmaf(ghs[t2][o2], ws2[e2][o2], lg);
    float s = (lg + G_b2[e2]) / 0.7f;                           // f32 div
    lgs[t2][e2] = fminf(fmaxf(s, -10.f), 10.f);
  }
  __syncthreads();

  if (wv == 0) {
    float uw[8];
#pragma unroll
    for (int e = 0; e < 8; ++e) uw[e] = 0.f;
    if (lane < 32) {
      int token = blockIdx.x * 32 + lane;
      float v[8];
#pragma unroll
      for (int e = 0; e < 8; ++e) v[e] = lgs[lane][e];
      float tv[4]; int ti[4]; unsigned msk = 0;
      for (int kk = 0; kk < 4; ++kk) {                          // ties -> lowest idx
        float best = -1e30f; int bi = 0;
        for (int e = 0; e < 8; ++e)
          if (!((msk >> e) & 1u) && v[e] > best) { best = v[e]; bi = e; }
        tv[kk] = best; ti[kk] = bi; msk |= 1u << bi;
      }
      float mx = tv[0], den = 0.f, wk4[4];
#pragma unroll
      for (int kk = 0; kk < 4; ++kk) { wk4[kk] = expf(tv[kk] - mx); den += wk4[kk]; }
#pragma unroll
      for (int e = 0; e < 8; ++e) {
        float val = 0.f;
#pragma unroll
        for (int kk = 0; kk < 4; ++kk) if (ti[kk] == e) val = wk4[kk] / den;
        w8full[(size_t)token * 8 + e] = val;
      }
      float dall = 0.f, pe[8];
#pragma unroll
      for (int e = 0; e < 8; ++e) { pe[e] = expf(v[e] - mx); dall += pe[e]; }
#pragma unroll
      for (int e = 0; e < 8; ++e) uw[e] = pe[e] / dall;
    }
    for (int m = 1; m <= 32; m <<= 1)
#pragma unroll
      for (int e = 0; e < 8; ++e) uw[e] += __shfl_xor(uw[e], m);
    if (lane == 0)
      for (int e = 0; e < 8; ++e) atomicAdd(usage + e, uw[e]);
  }
}

// ============== moe v2: group-per-wave, 8 waves, 16 tokens/block ==============
// waves 0..7 -> expert groups 0..7 (A0,A1,B0,B1,C0,C1,D0,D1) on a shared
// x tile; S-network split across all 8 waves by 16-col blocks (nt = wave).
// Private combine via LDS f32 atomics.
__global__ __launch_bounds__(512, 4) void moe_kernel(
    const float* __restrict__ x,
    const unsigned short* __restrict__ W1cat, const unsigned short* __restrict__ W2cat,
    const float* __restrict__ b1cat, const float* __restrict__ b2cat,
    const float* __restrict__ lng, const float* __restrict__ lnb,
    const float* __restrict__ bsc, const float* __restrict__ bbi,
    const float* __restrict__ w8full, float* __restrict__ out)
{
  // LDS: XS 8192 | HS 8*4096 | HS_S 4096 | pacc 8192 | partS 1024
  __shared__ unsigned char smem[54272];
  unsigned char* XS   = smem;
  unsigned char* HSb  = smem + 8192;
  unsigned char* HS_S = smem + 8192 + 32768;
  float* pacc_f = (float*)(smem + 8192 + 32768 + 4096);
  float* partS  = (float*)(smem + 8192 + 32768 + 4096 + 8192);  // [2][8][16]

  const int wv = threadIdx.x >> 6, lane = threadIdx.x & 63;
  const int l15 = lane & 15, l4 = lane >> 4;
  const int tb = blockIdx.x * 16;
  const int g = wv;

  // zero pacc
  for (int i = threadIdx.x; i < 2048; i += 512) pacc_f[i] = 0.f;
  // stage x tile (rows 0..15) bf16 swizzled — waves 0..3
  if (wv < 4) {
#pragma unroll
    for (int i = 0; i < 4; ++i) {
      int r = wv * 4 + i;
      const float4 v = *(const float4*)(x + (size_t)(tb + r) * 256 + lane * 4);
      float vv[4] = {v.x, v.y, v.z, v.w};
      us4 hi;
#pragma unroll
      for (int j = 0; j < 4; ++j) hi[j] = f2bf(vv[j]);
      int addr = r * 512 + ((((lane >> 1) ^ (r & 7)) << 4) | ((lane & 1) << 3));
      *(us4*)(XS + addr) = hi;
    }
  }
  __syncthreads();

  f32x4 zero = {0.f, 0.f, 0.f, 0.f};
  const float RS = 1.0f / sqrtf(1.0f + 1e-5f);
  unsigned char* HS = HSb + wv * 4096;

  // ---- this wave's expert group g ----
  {
    const unsigned short* W1 = W1cat + g * 32768;
    f32x4 acc[8];
#pragma unroll
    for (int nt = 0; nt < 8; ++nt) acc[nt] = zero;
    for (int ks = 0; ks < 8; ++ks) {
      int ar = l15 * 512 + ((((ks * 4 + l4) ^ (l15 & 7)) << 4));
      short8 a = *(const short8*)(XS + ar);
#pragma unroll
      for (int nt = 0; nt < 8; ++nt) {
        const short8 b = *(const short8*)(W1 + (nt * 16 + l15) * 256 + ks * 32 + l4 * 8);
        acc[nt] = MFMA16(a, b, acc[nt]);
      }
    }
    const float* b1 = b1cat + g * 128;
    const int type = (g < 2) ? 0 : (g < 4) ? 1 : (g < 6) ? 2 : 3;

    if (type == 2) {                        // C: gelu -> weighted pacc
#pragma unroll
      for (int r = 0; r < 4; ++r) {
        float wv_ = w8full[(size_t)(tb + l4 * 4 + r) * 8 + g];
#pragma unroll
        for (int nt = 0; nt < 8; ++nt) {
          float h = acc[nt][r] + b1[nt * 16 + l15];
          h = 0.5f * h * (1.0f + erff(h * 0.70710678118654752f));
          atomicAdd(&pacc_f[(l4 * 4 + r) * 128 + nt * 16 + l15], wv_ * h);
        }
      }
    } else {
#pragma unroll
      for (int r = 0; r < 4; ++r) {
#pragma unroll
        for (int nt = 0; nt < 8; ++nt) {
          float h = acc[nt][r] + b1[nt * 16 + l15];
          if (type == 0)      h = fmaxf(h, 0.f);
          else if (type == 1) {
            int col = (g - 2) * 128 + nt * 16 + l15;
            h = tanhf(h) * RS * bsc[col] + bbi[col];
          }
          else                h = h / (1.f + expf(-h));   // silu (D)
          acc[nt][r] = h;
        }
      }
      if (type == 3) {                      // D layernorm (in-wave shuffles)
        int li = g - 6;
#pragma unroll
        for (int r = 0; r < 4; ++r) {
          float s1 = 0.f, s2 = 0.f;
#pragma unroll
          for (int nt = 0; nt < 8; ++nt) { float h = acc[nt][r]; s1 += h; s2 += h * h; }
          for (int m = 1; m <= 8; m <<= 1) { s1 += __shfl_xor(s1, m); s2 += __shfl_xor(s2, m); }
          float mu = s1 * (1.f / 128.f);
          float var = s2 * (1.f / 128.f) - mu * mu;
          float sc = 1.f / sqrtf(var + 1e-5f);
#pragma unroll
          for (int nt = 0; nt < 8; ++nt) {
            int col = nt * 16 + l15;
            acc[nt][r] = (acc[nt][r] - mu) * sc * lng[li * 128 + col] + lnb[li * 128 + col];
          }
        }
      }
      // write h tile (bf16, swizzled, per-wave region)
#pragma unroll
      for (int r = 0; r < 4; ++r) {
        int row = l4 * 4 + r;
#pragma unroll
        for (int nt = 0; nt < 8; ++nt) {
          int bytecol = (nt * 16 + l15) * 2;
          int addr = row * 256 + ((((bytecol >> 4) ^ (row & 7)) << 4) | (bytecol & 15));
          *(unsigned short*)(HS + addr) = f2bf(acc[nt][r]);
        }
      }
      // GEMM2 (same wave; compiler inserts lgkmcnt)
      const int g2 = (g < 4) ? g : (g - 2);
      const unsigned short* W2 = W2cat + g2 * 16384;
      f32x4 acc2[8];
#pragma unroll
      for (int nt = 0; nt < 8; ++nt) acc2[nt] = zero;
      for (int ks = 0; ks < 4; ++ks) {
        int ar = l15 * 256 + ((((ks * 4 + l4) ^ (l15 & 7)) << 4));
        short8 a = *(const short8*)(HS + ar);
#pragma unroll
        for (int nt = 0; nt < 8; ++nt) {
          const short8 b = *(const short8*)(W2 + (nt * 16 + l15) * 128 + ks * 32 + l4 * 8);
          acc2[nt] = MFMA16(a, b, acc2[nt]);
        }
      }
      const float* b2 = b2cat + g2 * 128;
#pragma unroll
      for (int r = 0; r < 4; ++r) {
        float wv_ = w8full[(size_t)(tb + l4 * 4 + r) * 8 + g];
#pragma unroll
        for (int nt = 0; nt < 8; ++nt)
          atomicAdd(&pacc_f[(l4 * 4 + r) * 128 + nt * 16 + l15],
                    wv_ * (acc2[nt][r] + b2[nt * 16 + l15]));
      }
    }
  }

  // ---- S network, split by 16-col block: this wave handles nt = wv ----
  {
    const unsigned short* W1S = W1cat + 8 * 32768;
    f32x4 accS = zero;
    for (int ks = 0; ks < 8; ++ks) {
      int ar = l15 * 512 + ((((ks * 4 + l4) ^ (l15 & 7)) << 4));
      short8 a = *(const short8*)(XS + ar);
      const short8 b = *(const short8*)(W1S + (wv * 16 + l15) * 256 + ks * 32 + l4 * 8);
      accS = MFMA16(a, b, accS);
    }
    float bS = b1cat[8 * 128 + wv * 16 + l15];
#pragma unroll
    for (int r = 0; r < 4; ++r) accS[r] = fmaxf(accS[r] + bS, 0.f);
    // per-row partial sums over this wave's 16 cols
#pragma unroll
    for (int r = 0; r < 4; ++r) {
      float s1 = accS[r], s2 = accS[r] * accS[r];
      for (int m = 1; m <= 8; m <<= 1) { s1 += __shfl_xor(s1, m); s2 += __shfl_xor(s2, m); }
      if (l15 == 0) {
        partS[wv * 16 + l4 * 4 + r] = s1;
        partS[128 + wv * 16 + l4 * 4 + r] = s2;
      }
    }
    __syncthreads();
#pragma unroll
    for (int r = 0; r < 4; ++r) {
      int row = l4 * 4 + r;
      float s1 = 0.f, s2 = 0.f;
#pragma unroll
      for (int q = 0; q < 8; ++q) { s1 += partS[q * 16 + row]; s2 += partS[128 + q * 16 + row]; }
      float mu = s1 * (1.f / 128.f);
      float var = s2 * (1.f / 128.f) - mu * mu;
      float sc = 1.f / sqrtf(var + 1e-5f);
      int col = wv * 16 + l15;
      float hn = (accS[r] - mu) * sc * lng[2 * 128 + col] + lnb[2 * 128 + col];
      int bytecol = col * 2;
      int addr = row * 256 + ((((bytecol >> 4) ^ (row & 7)) << 4) | (bytecol & 15));
      *(unsigned short*)(HS_S + addr) = f2bf(hn);
    }
    __syncthreads();
    const unsigned short* W2S = W2cat + 6 * 16384;
    f32x4 acc2S = zero;
    for (int ks = 0; ks < 4; ++ks) {
      int ar = l15 * 256 + ((((ks * 4 + l4) ^ (l15 & 7)) << 4));
      short8 a = *(const short8*)(HS_S + ar);
      const short8 b = *(const short8*)(W2S + (wv * 16 + l15) * 128 + ks * 32 + l4 * 8);
      acc2S = MFMA16(a, b, acc2S);
    }
    float b2S = b2cat[6 * 128 + wv * 16 + l15];
#pragma unroll
    for (int r = 0; r < 4; ++r)
      out[(size_t)(tb + l4 * 4 + r) * 128 + wv * 16 + l15] = acc2S[r] + b2S;
  }

  __syncthreads();
  // private output
  for (int i = threadIdx.x; i < 2048; i += 512)
    out[4194304 + (size_t)tb * 128 + i] = pacc_f[i];
}

// ============== aux scalar ==============
__global__ void aux_kernel(const float* __restrict__ usage, float* __restrict__ out) {
  if (threadIdx.x == 0 && blockIdx.x == 0) {
    float a = 0.f;
    for (int e = 0; e < 8; ++e) {
      float u = usage[e] * (1.0f / 32768.0f);
      a += 0.125f * (logf(0.125f) - logf(u + 1e-10f));
    }
    out[8388608] = a * 0.125f;
  }
}

extern "C" void kernel_launch(void* const* d_in, const int* in_sizes, int n_in,
                              void* d_out, int out_size, void* d_ws, size_t ws_size,
                              hipStream_t stream) {
  (void)in_sizes; (void)n_in; (void)out_size; (void)ws_size;
  const float* x    = (const float*)d_in[0];
  const int*   mod  = (const int*)d_in[1];
  const float* A_W1 = (const float*)d_in[2];
  const float* A_b1 = (const float*)d_in[3];
  const float* A_W2 = (const float*)d_in[4];
  const float* A_b2 = (const float*)d_in[5];
  const float* B_W1 = (const float*)d_in[6];
  const float* B_b1 = (const float*)d_in[7];
  const float* B_g  = (const float*)d_in[8];
  const float* B_be = (const float*)d_in[9];
  const float* B_W2 = (const float*)d_in[10];
  const float* B_b2 = (const float*)d_in[11];
  const float* C_cw = (const float*)d_in[12];
  const float* C_cb = (const float*)d_in[13];
  const float* C_W  = (const float*)d_in[14];
  const float* C_b  = (const float*)d_in[15];
  const float* D_W1 = (const float*)d_in[16];
  const float* D_b1 = (const float*)d_in[17];
  const float* D_g  = (const float*)d_in[18];
  const float* D_be = (const float*)d_in[19];
  const float* D_W2 = (const float*)d_in[20];
  const float* D_b2 = (const float*)d_in[21];
  const float* S_W1 = (const float*)d_in[22];
  const float* S_b1 = (const float*)d_in[23];
  const float* S_g  = (const float*)d_in[24];
  const float* S_be = (const float*)d_in[25];
  const float* S_W2 = (const float*)d_in[26];
  const float* S_b2 = (const float*)d_in[27];
  const float* G_W1 = (const float*)d_in[28];
  const float* G_b1 = (const float*)d_in[29];
  const float* G_W2 = (const float*)d_in[30];
  const float* G_b2 = (const float*)d_in[31];

  char* ws = (char*)d_ws;
  unsigned short* W1cat = (unsigned short*)(ws + OFF_W1CAT);
  unsigned short* W2cat = (unsigned short*)(ws + OFF_W2CAT);
  float* W1T    = (float*)(ws + OFF_W1T);
  float* b1cat  = (float*)(ws + OFF_B1);
  float* b2cat  = (float*)(ws + OFF_B2);
  float* lng    = (float*)(ws + OFF_LNG);
  float* lnb    = (float*)(ws + OFF_LNB);
  float* bsc    = (float*)(ws + OFF_BSC);
  float* bbi    = (float*)(ws + OFF_BBI);
  float* usage  = (float*)(ws + OFF_USAGE);
  float* w8full = (float*)(ws + OFF_W8);
  float* out    = (float*)d_out;

  prep_kernel<<<1742, 256, 0, stream>>>(A_W1, A_b1, A_W2, A_b2, B_W1, B_b1, B_g, B_be,
      B_W2, B_b2, C_cw, C_cb, C_W, C_b, D_W1, D_b1, D_g, D_be, D_W2, D_b2,
      S_W1, S_b1, S_g, S_be, S_W2, S_b2, G_W1,
      W1cat, W2cat, W1T, b1cat, b2cat, lng, lnb, bsc, bbi, usage);
  gate_np_kernel<<<1024, 256, 0, stream>>>(x, mod, W1T, G_b1, G_W2, G_b2,
      w8full, usage);
  moe_kernel<<<2048, 512, 0, stream>>>(x, W1cat, W2cat, b1cat, b2cat, lng, lnb,
      bsc, bbi, w8full, out);
  aux_kernel<<<1, 64, 0, stream>>>(usage, out);
}

// Round 6
// 411.166 us; speedup vs baseline: 1.5741x; 1.1735x over previous
//
#include <hip/hip_runtime.h>
#include <hip/hip_bf16.h>
#include <math.h>

typedef __attribute__((ext_vector_type(8))) short short8;      // 8 bf16 (4 VGPRs)
typedef __attribute__((ext_vector_type(4))) float f32x4;       // MFMA acc
typedef __attribute__((ext_vector_type(4))) unsigned short us4;

#define MFMA16(a,b,c) __builtin_amdgcn_mfma_f32_16x16x32_bf16((a),(b),(c),0,0,0)

// ---------------- workspace layout (bytes) ----------------
// W1cat: bf16 fragment-ordered [9][ks=8][nt=8][lane=64][j=8]
// W2cat: bf16 fragment-ordered [7][ks=4][nt=8][lane=64][j=8]
#define OFF_W1CAT   0u
#define OFF_W2CAT   589824u
#define OFF_B1      950272u    // f32 [9][128]
#define OFF_B2      954880u    // f32 [7][128]
#define OFF_LNG     958464u    // f32 [3][128] (D0,D1,S gains)
#define OFF_LNB     960000u    // f32 [3][128]
#define OFF_BSC     961536u    // f32 [2][128] B_g
#define OFF_BBI     962560u    // f32 [2][128] B_be
#define OFF_USAGE   963584u    // f32 [8]
#define OFF_W8      963712u    // f32 [32768][8]
#define OFF_W1T     2012288u   // f32 [257][128]  gate W1 transposed

__device__ __forceinline__ unsigned short f2bf(float f) {
  union { float f; unsigned u; } v; v.f = f;
  return (unsigned short)((v.u + 0x7fffu + ((v.u >> 16) & 1u)) >> 16);
}

// ============== prep: pack weights (fragment-ordered), fold conv ==============
__global__ __launch_bounds__(256) void prep_kernel(
    const float* __restrict__ A_W1, const float* __restrict__ A_b1,
    const float* __restrict__ A_W2, const float* __restrict__ A_b2,
    const float* __restrict__ B_W1, const float* __restrict__ B_b1,
    const float* __restrict__ B_g,  const float* __restrict__ B_be,
    const float* __restrict__ B_W2, const float* __restrict__ B_b2,
    const float* __restrict__ C_cw, const float* __restrict__ C_cb,
    const float* __restrict__ C_W,  const float* __restrict__ C_b,
    const float* __restrict__ D_W1, const float* __restrict__ D_b1,
    const float* __restrict__ D_g,  const float* __restrict__ D_be,
    const float* __restrict__ D_W2, const float* __restrict__ D_b2,
    const float* __restrict__ S_W1, const float* __restrict__ S_b1,
    const float* __restrict__ S_g,  const float* __restrict__ S_be,
    const float* __restrict__ S_W2, const float* __restrict__ S_b2,
    const float* __restrict__ G_W1,
    unsigned short* __restrict__ W1cat, unsigned short* __restrict__ W2cat,
    float* __restrict__ W1T,
    float* __restrict__ b1cat, float* __restrict__ b2cat,
    float* __restrict__ lng, float* __restrict__ lnb,
    float* __restrict__ bsc, float* __restrict__ bbi,
    float* __restrict__ usage)
{
  int tid = blockIdx.x * 256 + threadIdx.x;
  if (tid < 294912) {                       // W1cat, fragment order
    int g = tid >> 15, rem = tid & 32767;
    int j = rem & 7, lane = (rem >> 3) & 63, nt = (rem >> 9) & 7, ks = rem >> 12;
    int p = nt * 16 + (lane & 15);
    int k = ks * 32 + (lane >> 4) * 8 + j;
    int src = p * 256 + k;
    float v;
    if (g < 2)      v = A_W1[g * 32768 + src];
    else if (g < 4) v = B_W1[(g - 2) * 32768 + src];
    else if (g < 6) {                       // Weff = conv folded into C_W
      int e = g - 4;
      v = 0.f;
      for (int c = 0; c < 4; ++c)
        for (int jj = 0; jj < 3; ++jj) {
          int h = k + 1 - jj;
          if (h >= 0 && h < 256)
            v += C_cw[e*12 + c*3 + jj] * C_W[e*131072 + p*1024 + c*256 + h];
        }
    }
    else if (g < 8) v = D_W1[(g - 6) * 32768 + src];
    else            v = S_W1[src];
    W1cat[tid] = f2bf(v);
    return;
  }
  tid -= 294912;
  if (tid < 114688) {                       // W2cat, fragment order
    int g = tid >> 14, rem = tid & 16383;
    int j = rem & 7, lane = (rem >> 3) & 63, nt = (rem >> 9) & 7, ks = rem >> 12;
    int p = nt * 16 + (lane & 15);
    int k = ks * 32 + (lane >> 4) * 8 + j;
    int src = p * 128 + k;
    float v;
    if (g < 2)      v = A_W2[g * 16384 + src];
    else if (g < 4) v = B_W2[(g - 2) * 16384 + src];
    else if (g < 6) v = D_W2[(g - 4) * 16384 + src];
    else            v = S_W2[src];
    W2cat[tid] = f2bf(v);
    return;
  }
  tid -= 114688;
  if (tid < 32896) {                        // W1T[k][o] = G_W1[o][k]
    int k = tid / 128, o = tid % 128;
    W1T[tid] = G_W1[o * 257 + k];
    return;
  }
  tid -= 32896;
  if (tid < 1152) {                         // b1cat (C fold added by prep2)
    int g = tid / 128, p = tid % 128;
    float v;
    if (g < 2)      v = A_b1[tid];
    else if (g < 4) v = B_b1[p + (g - 2) * 128];
    else if (g < 6) v = C_b[(g - 4) * 128 + p];
    else if (g < 8) v = D_b1[p + (g - 6) * 128];
    else            v = S_b1[p];
    b1cat[tid] = v;
    return;
  }
  tid -= 1152;
  if (tid < 896) {                          // b2cat
    int g = tid / 128, p = tid % 128;
    float v;
    if (g < 2)      v = A_b2[tid];
    else if (g < 4) v = B_b2[p + (g - 2) * 128];
    else if (g < 6) v = D_b2[p + (g - 4) * 128];
    else            v = S_b2[p];
    b2cat[tid] = v;
    return;
  }
  tid -= 896;
  if (tid < 768) {                          // LN gains/biases (D0,D1,S)
    if (tid < 384) {
      int j = tid / 128, p = tid % 128;
      lng[tid] = (j < 2) ? D_g[tid] : S_g[p];
    } else {
      int q = tid - 384; int j = q / 128, p = q % 128;
      lnb[q] = (j < 2) ? D_be[q] : S_be[p];
    }
    return;
  }
  tid -= 768;
  if (tid < 512) {                          // B scale/shift
    if (tid < 256) bsc[tid] = B_g[tid];
    else           bbi[tid - 256] = B_be[tid - 256];
    return;
  }
  tid -= 512;
  if (tid < 8) usage[tid] = 0.f;
}

// prep2: parallel conv-bias fold: b1cat[(4+e)*128+p] += C_cb[e][c] * sum_h C_W[e,p,c,:]
__global__ __launch_bounds__(256) void prep2_kernel(
    const float* __restrict__ C_cw_unused, const float* __restrict__ C_cb,
    const float* __restrict__ C_W, float* __restrict__ b1cat)
{
  int tid = blockIdx.x * 256 + threadIdx.x;   // 1024 threads: (e,p,c)
  int e = tid >> 9, rem = tid & 511;
  int p = rem >> 2, c = rem & 3;
  const float4* row = (const float4*)(C_W + e*131072 + p*1024 + c*256);
  float s = 0.f;
  for (int q = 0; q < 64; ++q) {
    float4 v = row[q];
    s += v.x + v.y + v.z + v.w;
  }
  atomicAdd(&b1cat[(4 + e) * 128 + p], C_cb[e * 4 + c] * s);
}

// ============== gate: o-on-lanes, token-in-registers; exact np FMA order ==============
// Same arithmetic per (t,o) as round-4/5 passing version; only the x fetch is
// restructured into wave-uniform float4 windows (s_load_dwordx4).
__global__ __launch_bounds__(256) void gate_np_kernel(
    const float* __restrict__ x, const int* __restrict__ modality,
    const float* __restrict__ W1T, const float* __restrict__ G_b1,
    const float* __restrict__ G_W2, const float* __restrict__ G_b2,
    float* __restrict__ w8full, float* __restrict__ usage)
{
  __shared__ float ghs[32][129];
  __shared__ float lgs[32][9];
  __shared__ float ws2[8][132];
  const int wv = threadIdx.x >> 6, lane = threadIdx.x & 63;
  const int tg = wv >> 1, hh = wv & 1;
  const int o = hh * 64 + lane;
  const int tbase = __builtin_amdgcn_readfirstlane(blockIdx.x * 32 + tg * 16);

  for (int i = threadIdx.x; i < 1024; i += 256)
    ws2[i >> 7][i & 127] = G_W2[i];

  float acc[16];
#pragma unroll
  for (int t = 0; t < 16; ++t) acc[t] = 0.f;

  const float* xb = x + (size_t)tbase * 256;
#pragma unroll 2
  for (int kq = 0; kq < 64; ++kq) {
    float4 xq[16];
#pragma unroll
    for (int t = 0; t < 16; ++t)
      xq[t] = *(const float4*)(xb + t * 256 + kq * 4);
#pragma unroll
    for (int kk = 0; kk < 4; ++kk) {
      float wk = W1T[(kq * 4 + kk) * 128 + o];
#pragma unroll
      for (int t = 0; t < 16; ++t)
        acc[t] = fmaf(xq[t][kk], wk, acc[t]);   // exact sequential-k order
    }
  }
  {
    float wm = W1T[256 * 128 + o];
#pragma unroll
    for (int t = 0; t < 16; ++t)
      acc[t] = fmaf((float)modality[tbase + t], wm, acc[t]);
  }
  float bo = G_b1[o];
#pragma unroll
  for (int t = 0; t < 16; ++t)
    ghs[tg * 16 + t][o] = (float)tanh((double)(acc[t] + bo));   // CR tanh -> f32
  __syncthreads();

  // layer 2: thread = (token t2, expert e2); sequential-o fmaf chain
  {
    const int t2 = threadIdx.x >> 3, e2 = threadIdx.x & 7;
    float lg = 0.f;
    for (int o2 = 0; o2 < 128; ++o2)
      lg = fmaf(ghs[t2][o2], ws2[e2][o2], lg);
    float s = (lg + G_b2[e2]) / 0.7f;                           // f32 div
    lgs[t2][e2] = fminf(fmaxf(s, -10.f), 10.f);
  }
  __syncthreads();

  if (wv == 0) {
    float uw[8];
#pragma unroll
    for (int e = 0; e < 8; ++e) uw[e] = 0.f;
    if (lane < 32) {
      int token = blockIdx.x * 32 + lane;
      float v[8];
#pragma unroll
      for (int e = 0; e < 8; ++e) v[e] = lgs[lane][e];
      float tv[4]; int ti[4]; unsigned msk = 0;
      for (int kk = 0; kk < 4; ++kk) {                          // ties -> lowest idx
        float best = -1e30f; int bi = 0;
        for (int e = 0; e < 8; ++e)
          if (!((msk >> e) & 1u) && v[e] > best) { best = v[e]; bi = e; }
        tv[kk] = best; ti[kk] = bi; msk |= 1u << bi;
      }
      float mx = tv[0], den = 0.f, wk4[4];
#pragma unroll
      for (int kk = 0; kk < 4; ++kk) { wk4[kk] = expf(tv[kk] - mx); den += wk4[kk]; }
#pragma unroll
      for (int e = 0; e < 8; ++e) {
        float val = 0.f;
#pragma unroll
        for (int kk = 0; kk < 4; ++kk) if (ti[kk] == e) val = wk4[kk] / den;
        w8full[(size_t)token * 8 + e] = val;
      }
      float dall = 0.f, pe[8];
#pragma unroll
      for (int e = 0; e < 8; ++e) { pe[e] = expf(v[e] - mx); dall += pe[e]; }
#pragma unroll
      for (int e = 0; e < 8; ++e) uw[e] = pe[e] / dall;
    }
    for (int m = 1; m <= 32; m <<= 1)
#pragma unroll
      for (int e = 0; e < 8; ++e) uw[e] += __shfl_xor(uw[e], m);
    if (lane == 0)
      for (int e = 0; e < 8; ++e) atomicAdd(usage + e, uw[e]);
  }
}

// ============== moe v3: group-per-wave + fragment-ordered (coalesced) weights ==============
__global__ __launch_bounds__(512, 4) void moe_kernel(
    const float* __restrict__ x,
    const unsigned short* __restrict__ W1cat, const unsigned short* __restrict__ W2cat,
    const float* __restrict__ b1cat, const float* __restrict__ b2cat,
    const float* __restrict__ lng, const float* __restrict__ lnb,
    const float* __restrict__ bsc, const float* __restrict__ bbi,
    const float* __restrict__ w8full, float* __restrict__ out)
{
  // LDS: XS 8192 | HS 8*4096 | HS_S 4096 | pacc 8192 | partS 1024
  __shared__ unsigned char smem[54272];
  unsigned char* XS   = smem;
  unsigned char* HSb  = smem + 8192;
  unsigned char* HS_S = smem + 8192 + 32768;
  float* pacc_f = (float*)(smem + 8192 + 32768 + 4096);
  float* partS  = (float*)(smem + 8192 + 32768 + 4096 + 8192);  // [2][8][16]

  const int wv = threadIdx.x >> 6, lane = threadIdx.x & 63;
  const int l15 = lane & 15, l4 = lane >> 4;
  const int tb = blockIdx.x * 16;
  const int g = wv;
  const short8* W1f = (const short8*)W1cat;   // [9*8][8][64] frags
  const short8* W2f = (const short8*)W2cat;   // [7*4][8][64] frags

  // zero pacc
  for (int i = threadIdx.x; i < 2048; i += 512) pacc_f[i] = 0.f;
  // stage x tile (rows 0..15) bf16 swizzled — waves 0..3
  if (wv < 4) {
#pragma unroll
    for (int i = 0; i < 4; ++i) {
      int r = wv * 4 + i;
      const float4 v = *(const float4*)(x + (size_t)(tb + r) * 256 + lane * 4);
      float vv[4] = {v.x, v.y, v.z, v.w};
      us4 hi;
#pragma unroll
      for (int j = 0; j < 4; ++j) hi[j] = f2bf(vv[j]);
      int addr = r * 512 + ((((lane >> 1) ^ (r & 7)) << 4) | ((lane & 1) << 3));
      *(us4*)(XS + addr) = hi;
    }
  }
  __syncthreads();

  f32x4 zero = {0.f, 0.f, 0.f, 0.f};
  const float RS = 1.0f / sqrtf(1.0f + 1e-5f);
  unsigned char* HS = HSb + wv * 4096;

  // ---- this wave's expert group g ----
  {
    f32x4 acc[8];
#pragma unroll
    for (int nt = 0; nt < 8; ++nt) acc[nt] = zero;
    for (int ks = 0; ks < 8; ++ks) {
      int ar = l15 * 512 + ((((ks * 4 + l4) ^ (l15 & 7)) << 4));
      short8 a = *(const short8*)(XS + ar);
      const short8* bp = W1f + ((size_t)(g * 8 + ks) * 8) * 64 + lane;
#pragma unroll
      for (int nt = 0; nt < 8; ++nt)
        acc[nt] = MFMA16(a, bp[nt * 64], acc[nt]);
    }
    const float* b1 = b1cat + g * 128;
    const int type = (g < 2) ? 0 : (g < 4) ? 1 : (g < 6) ? 2 : 3;

    if (type == 2) {                        // C: gelu -> weighted pacc
#pragma unroll
      for (int r = 0; r < 4; ++r) {
        float wv_ = w8full[(size_t)(tb + l4 * 4 + r) * 8 + g];
#pragma unroll
        for (int nt = 0; nt < 8; ++nt) {
          float h = acc[nt][r] + b1[nt * 16 + l15];
          h = 0.5f * h * (1.0f + erff(h * 0.70710678118654752f));
          atomicAdd(&pacc_f[(l4 * 4 + r) * 128 + nt * 16 + l15], wv_ * h);
        }
      }
    } else {
#pragma unroll
      for (int r = 0; r < 4; ++r) {
#pragma unroll
        for (int nt = 0; nt < 8; ++nt) {
          float h = acc[nt][r] + b1[nt * 16 + l15];
          if (type == 0)      h = fmaxf(h, 0.f);
          else if (type == 1) {
            int col = (g - 2) * 128 + nt * 16 + l15;
            h = tanhf(h) * RS * bsc[col] + bbi[col];
          }
          else                h = h / (1.f + expf(-h));   // silu (D)
          acc[nt][r] = h;
        }
      }
      if (type == 3) {                      // D layernorm (in-wave shuffles)
        int li = g - 6;
#pragma unroll
        for (int r = 0; r < 4; ++r) {
          float s1 = 0.f, s2 = 0.f;
#pragma unroll
          for (int nt = 0; nt < 8; ++nt) { float h = acc[nt][r]; s1 += h; s2 += h * h; }
          for (int m = 1; m <= 8; m <<= 1) { s1 += __shfl_xor(s1, m); s2 += __shfl_xor(s2, m); }
          float mu = s1 * (1.f / 128.f);
          float var = s2 * (1.f / 128.f) - mu * mu;
          float sc = 1.f / sqrtf(var + 1e-5f);
#pragma unroll
          for (int nt = 0; nt < 8; ++nt) {
            int col = nt * 16 + l15;
            acc[nt][r] = (acc[nt][r] - mu) * sc * lng[li * 128 + col] + lnb[li * 128 + col];
          }
        }
      }
      // write h tile (bf16, swizzled, per-wave region)
#pragma unroll
      for (int r = 0; r < 4; ++r) {
        int row = l4 * 4 + r;
#pragma unroll
        for (int nt = 0; nt < 8; ++nt) {
          int bytecol = (nt * 16 + l15) * 2;
          int addr = row * 256 + ((((bytecol >> 4) ^ (row & 7)) << 4) | (bytecol & 15));
          *(unsigned short*)(HS + addr) = f2bf(acc[nt][r]);
        }
      }
      // GEMM2
      const int g2 = (g < 4) ? g : (g - 2);
      f32x4 acc2[8];
#pragma unroll
      for (int nt = 0; nt < 8; ++nt) acc2[nt] = zero;
      for (int ks = 0; ks < 4; ++ks) {
        int ar = l15 * 256 + ((((ks * 4 + l4) ^ (l15 & 7)) << 4));
        short8 a = *(const short8*)(HS + ar);
        const short8* bp = W2f + ((size_t)(g2 * 4 + ks) * 8) * 64 + lane;
#pragma unroll
        for (int nt = 0; nt < 8; ++nt)
          acc2[nt] = MFMA16(a, bp[nt * 64], acc2[nt]);
      }
      const float* b2 = b2cat + g2 * 128;
#pragma unroll
      for (int r = 0; r < 4; ++r) {
        float wv_ = w8full[(size_t)(tb + l4 * 4 + r) * 8 + g];
#pragma unroll
        for (int nt = 0; nt < 8; ++nt)
          atomicAdd(&pacc_f[(l4 * 4 + r) * 128 + nt * 16 + l15],
                    wv_ * (acc2[nt][r] + b2[nt * 16 + l15]));
      }
    }
  }

  // ---- S network, split by 16-col block: this wave handles nt = wv ----
  {
    f32x4 accS = zero;
    for (int ks = 0; ks < 8; ++ks) {
      int ar = l15 * 512 + ((((ks * 4 + l4) ^ (l15 & 7)) << 4));
      short8 a = *(const short8*)(XS + ar);
      const short8 b = W1f[((size_t)(8 * 8 + ks) * 8 + wv) * 64 + lane];
      accS = MFMA16(a, b, accS);
    }
    float bS = b1cat[8 * 128 + wv * 16 + l15];
#pragma unroll
    for (int r = 0; r < 4; ++r) accS[r] = fmaxf(accS[r] + bS, 0.f);
    // per-row partial sums over this wave's 16 cols
#pragma unroll
    for (int r = 0; r < 4; ++r) {
      float s1 = accS[r], s2 = accS[r] * accS[r];
      for (int m = 1; m <= 8; m <<= 1) { s1 += __shfl_xor(s1, m); s2 += __shfl_xor(s2, m); }
      if (l15 == 0) {
        partS[wv * 16 + l4 * 4 + r] = s1;
        partS[128 + wv * 16 + l4 * 4 + r] = s2;
      }
    }
    __syncthreads();
#pragma unroll
    for (int r = 0; r < 4; ++r) {
      int row = l4 * 4 + r;
      float s1 = 0.f, s2 = 0.f;
#pragma unroll
      for (int q = 0; q < 8; ++q) { s1 += partS[q * 16 + row]; s2 += partS[128 + q * 16 + row]; }
      float mu = s1 * (1.f / 128.f);
      float var = s2 * (1.f / 128.f) - mu * mu;
      float sc = 1.f / sqrtf(var + 1e-5f);
      int col = wv * 16 + l15;
      float hn = (accS[r] - mu) * sc * lng[2 * 128 + col] + lnb[2 * 128 + col];
      int bytecol = col * 2;
      int addr = row * 256 + ((((bytecol >> 4) ^ (row & 7)) << 4) | (bytecol & 15));
      *(unsigned short*)(HS_S + addr) = f2bf(hn);
    }
    __syncthreads();
    f32x4 acc2S = zero;
    for (int ks = 0; ks < 4; ++ks) {
      int ar = l15 * 256 + ((((ks * 4 + l4) ^ (l15 & 7)) << 4));
      short8 a = *(const short8*)(HS_S + ar);
      const short8 b = W2f[((size_t)(6 * 4 + ks) * 8 + wv) * 64 + lane];
      acc2S = MFMA16(a, b, acc2S);
    }
    float b2S = b2cat[6 * 128 + wv * 16 + l15];
#pragma unroll
    for (int r = 0; r < 4; ++r)
      out[(size_t)(tb + l4 * 4 + r) * 128 + wv * 16 + l15] = acc2S[r] + b2S;
  }

  __syncthreads();
  // private output
  for (int i = threadIdx.x; i < 2048; i += 512)
    out[4194304 + (size_t)tb * 128 + i] = pacc_f[i];
}

// ============== aux scalar ==============
__global__ void aux_kernel(const float* __restrict__ usage, float* __restrict__ out) {
  if (threadIdx.x == 0 && blockIdx.x == 0) {
    float a = 0.f;
    for (int e = 0; e < 8; ++e) {
      float u = usage[e] * (1.0f / 32768.0f);
      a += 0.125f * (logf(0.125f) - logf(u + 1e-10f));
    }
    out[8388608] = a * 0.125f;
  }
}

extern "C" void kernel_launch(void* const* d_in, const int* in_sizes, int n_in,
                              void* d_out, int out_size, void* d_ws, size_t ws_size,
                              hipStream_t stream) {
  (void)in_sizes; (void)n_in; (void)out_size; (void)ws_size;
  const float* x    = (const float*)d_in[0];
  const int*   mod  = (const int*)d_in[1];
  const float* A_W1 = (const float*)d_in[2];
  const float* A_b1 = (const float*)d_in[3];
  const float* A_W2 = (const float*)d_in[4];
  const float* A_b2 = (const float*)d_in[5];
  const float* B_W1 = (const float*)d_in[6];
  const float* B_b1 = (const float*)d_in[7];
  const float* B_g  = (const float*)d_in[8];
  const float* B_be = (const float*)d_in[9];
  const float* B_W2 = (const float*)d_in[10];
  const float* B_b2 = (const float*)d_in[11];
  const float* C_cw = (const float*)d_in[12];
  const float* C_cb = (const float*)d_in[13];
  const float* C_W  = (const float*)d_in[14];
  const float* C_b  = (const float*)d_in[15];
  const float* D_W1 = (const float*)d_in[16];
  const float* D_b1 = (const float*)d_in[17];
  const float* D_g  = (const float*)d_in[18];
  const float* D_be = (const float*)d_in[19];
  const float* D_W2 = (const float*)d_in[20];
  const float* D_b2 = (const float*)d_in[21];
  const float* S_W1 = (const float*)d_in[22];
  const float* S_b1 = (const float*)d_in[23];
  const float* S_g  = (const float*)d_in[24];
  const float* S_be = (const float*)d_in[25];
  const float* S_W2 = (const float*)d_in[26];
  const float* S_b2 = (const float*)d_in[27];
  const float* G_W1 = (const float*)d_in[28];
  const float* G_b1 = (const float*)d_in[29];
  const float* G_W2 = (const float*)d_in[30];
  const float* G_b2 = (const float*)d_in[31];

  char* ws = (char*)d_ws;
  unsigned short* W1cat = (unsigned short*)(ws + OFF_W1CAT);
  unsigned short* W2cat = (unsigned short*)(ws + OFF_W2CAT);
  float* W1T    = (float*)(ws + OFF_W1T);
  float* b1cat  = (float*)(ws + OFF_B1);
  float* b2cat  = (float*)(ws + OFF_B2);
  float* lng    = (float*)(ws + OFF_LNG);
  float* lnb    = (float*)(ws + OFF_LNB);
  float* bsc    = (float*)(ws + OFF_BSC);
  float* bbi    = (float*)(ws + OFF_BBI);
  float* usage  = (float*)(ws + OFF_USAGE);
  float* w8full = (float*)(ws + OFF_W8);
  float* out    = (float*)d_out;

  prep_kernel<<<1742, 256, 0, stream>>>(A_W1, A_b1, A_W2, A_b2, B_W1, B_b1, B_g, B_be,
      B_W2, B_b2, C_cw, C_cb, C_W, C_b, D_W1, D_b1, D_g, D_be, D_W2, D_b2,
      S_W1, S_b1, S_g, S_be, S_W2, S_b2, G_W1,
      W1cat, W2cat, W1T, b1cat, b2cat, lng, lnb, bsc, bbi, usage);
  prep2_kernel<<<4, 256, 0, stream>>>(C_cw, C_cb, C_W, b1cat);
  gate_np_kernel<<<1024, 256, 0, stream>>>(x, mod, W1T, G_b1, G_W2, G_b2,
      w8full, usage);
  moe_kernel<<<2048, 512, 0, stream>>>(x, W1cat, W2cat, b1cat, b2cat, lng, lnb,
      bsc, bbi, w8full, out);
  aux_kernel<<<1, 64, 0, stream>>>(usage, out);
}

// Round 7
// 396.002 us; speedup vs baseline: 1.6343x; 1.0383x over previous
//
#include <hip/hip_runtime.h>
#include <hip/hip_bf16.h>
#include <math.h>

typedef __attribute__((ext_vector_type(8))) short short8;      // 8 bf16 (4 VGPRs)
typedef __attribute__((ext_vector_type(4))) float f32x4;       // MFMA acc
typedef __attribute__((ext_vector_type(4))) unsigned short us4;

#define MFMA16(a,b,c) __builtin_amdgcn_mfma_f32_16x16x32_bf16((a),(b),(c),0,0,0)

// ---------------- workspace layout (bytes) ----------------
// W1cat: bf16 fragment-ordered [9][ks=8][nt=8][lane=64][j=8]
// W2cat: bf16 fragment-ordered [7][ks=4][nt=8][lane=64][j=8]
#define OFF_W1CAT   0u
#define OFF_W2CAT   589824u
#define OFF_B1      950272u    // f32 [9][128]
#define OFF_B2      954880u    // f32 [7][128]
#define OFF_LNG     958464u    // f32 [3][128] (D0,D1,S gains)
#define OFF_LNB     960000u    // f32 [3][128]
#define OFF_BSC     961536u    // f32 [2][128] B_g
#define OFF_BBI     962560u    // f32 [2][128] B_be
#define OFF_USAGE   963584u    // f32 [8]
#define OFF_W8      963712u    // f32 [32768][8]
#define OFF_W1T     2012288u   // f32 [257][128]  gate W1 transposed

__device__ __forceinline__ unsigned short f2bf(float f) {
  union { float f; unsigned u; } v; v.f = f;
  return (unsigned short)((v.u + 0x7fffu + ((v.u >> 16) & 1u)) >> 16);
}

// ============== prep: pack weights (fragment-ordered), fold conv ==============
__global__ __launch_bounds__(256) void prep_kernel(
    const float* __restrict__ A_W1, const float* __restrict__ A_b1,
    const float* __restrict__ A_W2, const float* __restrict__ A_b2,
    const float* __restrict__ B_W1, const float* __restrict__ B_b1,
    const float* __restrict__ B_g,  const float* __restrict__ B_be,
    const float* __restrict__ B_W2, const float* __restrict__ B_b2,
    const float* __restrict__ C_cw, const float* __restrict__ C_cb,
    const float* __restrict__ C_W,  const float* __restrict__ C_b,
    const float* __restrict__ D_W1, const float* __restrict__ D_b1,
    const float* __restrict__ D_g,  const float* __restrict__ D_be,
    const float* __restrict__ D_W2, const float* __restrict__ D_b2,
    const float* __restrict__ S_W1, const float* __restrict__ S_b1,
    const float* __restrict__ S_g,  const float* __restrict__ S_be,
    const float* __restrict__ S_W2, const float* __restrict__ S_b2,
    const float* __restrict__ G_W1,
    unsigned short* __restrict__ W1cat, unsigned short* __restrict__ W2cat,
    float* __restrict__ W1T,
    float* __restrict__ b1cat, float* __restrict__ b2cat,
    float* __restrict__ lng, float* __restrict__ lnb,
    float* __restrict__ bsc, float* __restrict__ bbi,
    float* __restrict__ usage)
{
  int tid = blockIdx.x * 256 + threadIdx.x;
  if (tid < 294912) {                       // W1cat, fragment order
    int g = tid >> 15, rem = tid & 32767;
    int j = rem & 7, lane = (rem >> 3) & 63, nt = (rem >> 9) & 7, ks = rem >> 12;
    int p = nt * 16 + (lane & 15);
    int k = ks * 32 + (lane >> 4) * 8 + j;
    int src = p * 256 + k;
    float v;
    if (g < 2)      v = A_W1[g * 32768 + src];
    else if (g < 4) v = B_W1[(g - 2) * 32768 + src];
    else if (g < 6) {                       // Weff = conv folded into C_W
      int e = g - 4;
      v = 0.f;
      for (int c = 0; c < 4; ++c)
        for (int jj = 0; jj < 3; ++jj) {
          int h = k + 1 - jj;
          if (h >= 0 && h < 256)
            v += C_cw[e*12 + c*3 + jj] * C_W[e*131072 + p*1024 + c*256 + h];
        }
    }
    else if (g < 8) v = D_W1[(g - 6) * 32768 + src];
    else            v = S_W1[src];
    W1cat[tid] = f2bf(v);
    return;
  }
  tid -= 294912;
  if (tid < 114688) {                       // W2cat, fragment order
    int g = tid >> 14, rem = tid & 16383;
    int j = rem & 7, lane = (rem >> 3) & 63, nt = (rem >> 9) & 7, ks = rem >> 12;
    int p = nt * 16 + (lane & 15);
    int k = ks * 32 + (lane >> 4) * 8 + j;
    int src = p * 128 + k;
    float v;
    if (g < 2)      v = A_W2[g * 16384 + src];
    else if (g < 4) v = B_W2[(g - 2) * 16384 + src];
    else if (g < 6) v = D_W2[(g - 4) * 16384 + src];
    else            v = S_W2[src];
    W2cat[tid] = f2bf(v);
    return;
  }
  tid -= 114688;
  if (tid < 32896) {                        // W1T[k][o] = G_W1[o][k]
    int k = tid / 128, o = tid % 128;
    W1T[tid] = G_W1[o * 257 + k];
    return;
  }
  tid -= 32896;
  if (tid < 1152) {                         // b1cat (C fold added by prep2)
    int g = tid / 128, p = tid % 128;
    float v;
    if (g < 2)      v = A_b1[tid];
    else if (g < 4) v = B_b1[p + (g - 2) * 128];
    else if (g < 6) v = C_b[(g - 4) * 128 + p];
    else if (g < 8) v = D_b1[p + (g - 6) * 128];
    else            v = S_b1[p];
    b1cat[tid] = v;
    return;
  }
  tid -= 1152;
  if (tid < 896) {                          // b2cat
    int g = tid / 128, p = tid % 128;
    float v;
    if (g < 2)      v = A_b2[tid];
    else if (g < 4) v = B_b2[p + (g - 2) * 128];
    else if (g < 6) v = D_b2[p + (g - 4) * 128];
    else            v = S_b2[p];
    b2cat[tid] = v;
    return;
  }
  tid -= 896;
  if (tid < 768) {                          // LN gains/biases (D0,D1,S)
    if (tid < 384) {
      int j = tid / 128, p = tid % 128;
      lng[tid] = (j < 2) ? D_g[tid] : S_g[p];
    } else {
      int q = tid - 384; int j = q / 128, p = q % 128;
      lnb[q] = (j < 2) ? D_be[q] : S_be[p];
    }
    return;
  }
  tid -= 768;
  if (tid < 512) {                          // B scale/shift
    if (tid < 256) bsc[tid] = B_g[tid];
    else           bbi[tid - 256] = B_be[tid - 256];
    return;
  }
  tid -= 512;
  if (tid < 8) usage[tid] = 0.f;
}

// prep2: parallel conv-bias fold
__global__ __launch_bounds__(256) void prep2_kernel(
    const float* __restrict__ C_cw_unused, const float* __restrict__ C_cb,
    const float* __restrict__ C_W, float* __restrict__ b1cat)
{
  int tid = blockIdx.x * 256 + threadIdx.x;   // 1024 threads: (e,p,c)
  int e = tid >> 9, rem = tid & 511;
  int p = rem >> 2, c = rem & 3;
  const float4* row = (const float4*)(C_W + e*131072 + p*1024 + c*256);
  float s = 0.f;
  for (int q = 0; q < 64; ++q) {
    float4 v = row[q];
    s += v.x + v.y + v.z + v.w;
  }
  atomicAdd(&b1cat[(4 + e) * 128 + p], C_cb[e * 4 + c] * s);
}

// ============== gate v3: token-on-lane, o-chains, exact np FMA order ==============
// Block = 512 thr = 8 waves, 64 tokens. Wave w owns outputs o in [w*16, w*16+16).
// Lane = token. x staged transposed+swizzled in LDS (exact f32); W1T rows are
// wave-uniform scalar loads. Per (t,o): sequential-k fmaf chain k=0..255 then
// modality column -> +b1 -> f64 tanh -> f32. Layer 2: thread=(t,e) sequential-o.
__global__ __launch_bounds__(512) void gate_np_kernel(
    const float* __restrict__ x, const int* __restrict__ modality,
    const float* __restrict__ W1T, const float* __restrict__ G_b1,
    const float* __restrict__ G_W2, const float* __restrict__ G_b2,
    float* __restrict__ w8full, float* __restrict__ usage)
{
  __shared__ unsigned char Ubuf[33024];     // xs [128][64] f32 (32KB) / ghs [64][129]
  __shared__ float ws2[8][132];
  __shared__ float lgs[64][9];
  float* xs  = (float*)Ubuf;
  float* ghs = (float*)Ubuf;
  const int tid = threadIdx.x;
  const int wv = __builtin_amdgcn_readfirstlane(tid >> 6);
  const int lane = tid & 63;
  const int tb = blockIdx.x * 64;
  const int o0 = wv * 16;
  const int t = lane;

  for (int i = tid; i < 1024; i += 512) ws2[i >> 7][i & 127] = G_W2[i];

  float acc[16];
#pragma unroll
  for (int j = 0; j < 16; ++j) acc[j] = 0.f;

  for (int p = 0; p < 2; ++p) {
    __syncthreads();                        // previous phase fully consumed
    // stage x[tb+tt][p*128 + k'] -> xs[k'][tt ^ swz(k')]
#pragma unroll
    for (int it = 0; it < 4; ++it) {
      int f = it * 512 + tid;               // float4 index in [64 rows][32 f4]
      int tt = f >> 5, c4 = f & 31;
      int kk = c4 * 4;
      const float4 v = *(const float4*)(x + (size_t)(tb + tt) * 256 + p * 128 + kk);
      int col = tt ^ (((kk >> 4) & 7) << 3);
      xs[(kk + 0) * 64 + col] = v.x;
      xs[(kk + 1) * 64 + col] = v.y;
      xs[(kk + 2) * 64 + col] = v.z;
      xs[(kk + 3) * 64 + col] = v.w;
    }
    __syncthreads();
    const float* wbase = W1T + (size_t)(p * 128) * 128 + o0;
    for (int kk = 0; kk < 128; ++kk) {
      float xv = xs[kk * 64 + (t ^ (((kk >> 4) & 7) << 3))];
      const float* wk = wbase + (size_t)kk * 128;
#pragma unroll
      for (int j = 0; j < 16; ++j)
        acc[j] = fmaf(xv, wk[j], acc[j]);   // exact sequential-k chain
    }
  }
  {
    float xv = (float)modality[tb + t];     // k = 256 (mod column)
    const float* wk = W1T + (size_t)256 * 128 + o0;
#pragma unroll
    for (int j = 0; j < 16; ++j)
      acc[j] = fmaf(xv, wk[j], acc[j]);
  }
  __syncthreads();                          // xs dead -> reuse as ghs
#pragma unroll
  for (int j = 0; j < 16; ++j)
    ghs[t * 129 + o0 + j] = (float)tanh((double)(acc[j] + G_b1[o0 + j]));
  __syncthreads();

  // layer 2: thread = (token, expert), sequential-o fmaf chain
  {
    int t2 = tid >> 3, e2 = tid & 7;
    float lg = 0.f;
    for (int o2 = 0; o2 < 128; ++o2)
      lg = fmaf(ghs[t2 * 129 + o2], ws2[e2][o2], lg);
    float s = (lg + G_b2[e2]) / 0.7f;       // f32 div
    lgs[t2][e2] = fminf(fmaxf(s, -10.f), 10.f);
  }
  __syncthreads();

  if (wv == 0) {                            // 64 tokens on 64 lanes
    int token = tb + lane;
    float v[8];
#pragma unroll
    for (int e = 0; e < 8; ++e) v[e] = lgs[lane][e];
    float tv[4]; int ti[4]; unsigned msk = 0;
    for (int kk = 0; kk < 4; ++kk) {        // ties -> lowest idx
      float best = -1e30f; int bi = 0;
      for (int e = 0; e < 8; ++e)
        if (!((msk >> e) & 1u) && v[e] > best) { best = v[e]; bi = e; }
      tv[kk] = best; ti[kk] = bi; msk |= 1u << bi;
    }
    float mx = tv[0], den = 0.f, wk4[4];
#pragma unroll
    for (int kk = 0; kk < 4; ++kk) { wk4[kk] = expf(tv[kk] - mx); den += wk4[kk]; }
#pragma unroll
    for (int e = 0; e < 8; ++e) {
      float val = 0.f;
#pragma unroll
      for (int kk = 0; kk < 4; ++kk) if (ti[kk] == e) val = wk4[kk] / den;
      w8full[(size_t)token * 8 + e] = val;
    }
    float uw[8];
    float dall = 0.f, pe[8];
#pragma unroll
    for (int e = 0; e < 8; ++e) { pe[e] = expf(v[e] - mx); dall += pe[e]; }
#pragma unroll
    for (int e = 0; e < 8; ++e) uw[e] = pe[e] / dall;
    for (int m = 1; m <= 32; m <<= 1)
#pragma unroll
      for (int e = 0; e < 8; ++e) uw[e] += __shfl_xor(uw[e], m);
    if (lane == 0)
      for (int e = 0; e < 8; ++e) atomicAdd(usage + e, uw[e]);
  }
}

// ============== moe v5: tile-per-wave (32 tokens), A-frags in registers ==============
// Block = 2 waves = 64 tokens; each wave loops all 9 groups + GEMM2, combine in
// registers. Weight B-frags coalesced (fragment-ordered) and shared across the
// wave's 2 tiles. One barrier per group keeps the 2 waves lockstep (L1 dedup).
__global__ __launch_bounds__(128) void moe_kernel(
    const float* __restrict__ x,
    const unsigned short* __restrict__ W1cat, const unsigned short* __restrict__ W2cat,
    const float* __restrict__ b1cat, const float* __restrict__ b2cat,
    const float* __restrict__ lng, const float* __restrict__ lnb,
    const float* __restrict__ bsc, const float* __restrict__ bbi,
    const float* __restrict__ w8full, float* __restrict__ out)
{
  __shared__ unsigned char smem[2][8192];   // per-wave HS: [2 tiles][16][256B]
  const int wv = threadIdx.x >> 6, lane = threadIdx.x & 63;
  const int l15 = lane & 15, l4 = lane >> 4;
  const int tb = (blockIdx.x * 2 + wv) * 32;
  unsigned char* HS = smem[wv];

  const short8* W1f = (const short8*)W1cat;
  const short8* W2f = (const short8*)W2cat;

  // A-fragments for both 16-token tiles, all 8 k-slices, in registers.
  // a[j] = bf16(x[row=l15][k=ks*32+l4*8+j]) — identical values to LDS path.
  short8 A0[8], A1[8];
#pragma unroll
  for (int ks = 0; ks < 8; ++ks) {
    int k0 = ks * 32 + l4 * 8;
    const float* xr0 = x + (size_t)(tb + l15) * 256 + k0;
    const float* xr1 = x + (size_t)(tb + 16 + l15) * 256 + k0;
    float4 u0 = *(const float4*)(xr0), v0 = *(const float4*)(xr0 + 4);
    float4 u1 = *(const float4*)(xr1), v1 = *(const float4*)(xr1 + 4);
    short8 a0, a1;
    a0[0]=(short)f2bf(u0.x); a0[1]=(short)f2bf(u0.y); a0[2]=(short)f2bf(u0.z); a0[3]=(short)f2bf(u0.w);
    a0[4]=(short)f2bf(v0.x); a0[5]=(short)f2bf(v0.y); a0[6]=(short)f2bf(v0.z); a0[7]=(short)f2bf(v0.w);
    a1[0]=(short)f2bf(u1.x); a1[1]=(short)f2bf(u1.y); a1[2]=(short)f2bf(u1.z); a1[3]=(short)f2bf(u1.w);
    a1[4]=(short)f2bf(v1.x); a1[5]=(short)f2bf(v1.y); a1[6]=(short)f2bf(v1.z); a1[7]=(short)f2bf(v1.w);
    A0[ks] = a0; A1[ks] = a1;
  }

  f32x4 zero = {0.f, 0.f, 0.f, 0.f};
  f32x4 pacc0[8], pacc1[8];
#pragma unroll
  for (int nt = 0; nt < 8; ++nt) { pacc0[nt] = zero; pacc1[nt] = zero; }
  const float RS = 1.0f / sqrtf(1.0f + 1e-5f);

  for (int g = 0; g < 9; ++g) {
    __syncthreads();                        // keep block's waves lockstep
    f32x4 acc0[8], acc1[8];
#pragma unroll
    for (int nt = 0; nt < 8; ++nt) { acc0[nt] = zero; acc1[nt] = zero; }
#pragma unroll
    for (int ks = 0; ks < 8; ++ks) {
      const short8* bp = W1f + (size_t)((g * 8 + ks) * 8) * 64 + lane;
#pragma unroll
      for (int nt = 0; nt < 8; ++nt) {
        short8 b = bp[nt * 64];
        acc0[nt] = MFMA16(A0[ks], b, acc0[nt]);
        acc1[nt] = MFMA16(A1[ks], b, acc1[nt]);
      }
    }
    const float* b1 = b1cat + g * 128;

    if (g == 4 || g == 5) {                 // C: gelu -> weighted combine, no GEMM2
#pragma unroll
      for (int tt = 0; tt < 2; ++tt)
#pragma unroll
        for (int r = 0; r < 4; ++r) {
          float wv_ = w8full[(size_t)(tb + tt * 16 + l4 * 4 + r) * 8 + g];
#pragma unroll
          for (int nt = 0; nt < 8; ++nt) {
            float h = (tt ? acc1[nt][r] : acc0[nt][r]) + b1[nt * 16 + l15];
            h = 0.5f * h * (1.0f + erff(h * 0.70710678118654752f));
            if (tt) pacc1[nt][r] += wv_ * h; else pacc0[nt][r] += wv_ * h;
          }
        }
      continue;
    }
    // activation
#pragma unroll
    for (int tt = 0; tt < 2; ++tt)
#pragma unroll
      for (int r = 0; r < 4; ++r)
#pragma unroll
        for (int nt = 0; nt < 8; ++nt) {
          float h = (tt ? acc1[nt][r] : acc0[nt][r]) + b1[nt * 16 + l15];
          if (g < 2)      h = fmaxf(h, 0.f);
          else if (g < 4) {
            int col = (g - 2) * 128 + nt * 16 + l15;
            h = tanhf(h) * RS * bsc[col] + bbi[col];
          }
          else if (g < 8) h = h / (1.f + expf(-h));   // silu (D)
          else            h = fmaxf(h, 0.f);          // S: relu
          if (tt) acc1[nt][r] = h; else acc0[nt][r] = h;
        }
    if (g >= 6) {                           // layernorm (D0,D1,S) in-wave
      int li = (g == 8) ? 2 : (g - 6);
#pragma unroll
      for (int tt = 0; tt < 2; ++tt)
#pragma unroll
        for (int r = 0; r < 4; ++r) {
          float s1 = 0.f, s2 = 0.f;
#pragma unroll
          for (int nt = 0; nt < 8; ++nt) {
            float h = tt ? acc1[nt][r] : acc0[nt][r];
            s1 += h; s2 += h * h;
          }
          for (int m = 1; m <= 8; m <<= 1) { s1 += __shfl_xor(s1, m); s2 += __shfl_xor(s2, m); }
          float mu = s1 * (1.f / 128.f);
          float var = s2 * (1.f / 128.f) - mu * mu;
          float sc = 1.f / sqrtf(var + 1e-5f);
#pragma unroll
          for (int nt = 0; nt < 8; ++nt) {
            int col = nt * 16 + l15;
            float h = tt ? acc1[nt][r] : acc0[nt][r];
            h = (h - mu) * sc * lng[li * 128 + col] + lnb[li * 128 + col];
            if (tt) acc1[nt][r] = h; else acc0[nt][r] = h;
          }
        }
    }
    // write h tiles (bf16, swizzled) to per-wave HS
#pragma unroll
    for (int tt = 0; tt < 2; ++tt)
#pragma unroll
      for (int r = 0; r < 4; ++r) {
        int row = l4 * 4 + r;
#pragma unroll
        for (int nt = 0; nt < 8; ++nt) {
          int bytecol = (nt * 16 + l15) * 2;
          int addr = tt * 4096 + row * 256 +
                     ((((bytecol >> 4) ^ (row & 7)) << 4) | (bytecol & 15));
          *(unsigned short*)(HS + addr) = f2bf(tt ? acc1[nt][r] : acc0[nt][r]);
        }
      }
    // GEMM2 (same wave; in-order LDS + compiler lgkmcnt)
    const int g2 = (g < 4) ? g : ((g == 8) ? 6 : g - 2);
    f32x4 acc2_0[8], acc2_1[8];
#pragma unroll
    for (int nt = 0; nt < 8; ++nt) { acc2_0[nt] = zero; acc2_1[nt] = zero; }
#pragma unroll
    for (int ks = 0; ks < 4; ++ks) {
      int ar = l15 * 256 + ((((ks * 4 + l4) ^ (l15 & 7)) << 4));
      short8 a0 = *(const short8*)(HS + ar);
      short8 a1 = *(const short8*)(HS + 4096 + ar);
      const short8* bp = W2f + (size_t)((g2 * 4 + ks) * 8) * 64 + lane;
#pragma unroll
      for (int nt = 0; nt < 8; ++nt) {
        short8 b = bp[nt * 64];
        acc2_0[nt] = MFMA16(a0, b, acc2_0[nt]);
        acc2_1[nt] = MFMA16(a1, b, acc2_1[nt]);
      }
    }
    const float* b2 = b2cat + g2 * 128;
    if (g == 8) {                           // shared output direct
#pragma unroll
      for (int tt = 0; tt < 2; ++tt)
#pragma unroll
        for (int r = 0; r < 4; ++r) {
          int token = tb + tt * 16 + l4 * 4 + r;
#pragma unroll
          for (int nt = 0; nt < 8; ++nt)
            out[(size_t)token * 128 + nt * 16 + l15] =
                (tt ? acc2_1[nt][r] : acc2_0[nt][r]) + b2[nt * 16 + l15];
        }
    } else {                                // weighted combine into register pacc
#pragma unroll
      for (int tt = 0; tt < 2; ++tt)
#pragma unroll
        for (int r = 0; r < 4; ++r) {
          float wv_ = w8full[(size_t)(tb + tt * 16 + l4 * 4 + r) * 8 + g];
#pragma unroll
          for (int nt = 0; nt < 8; ++nt) {
            float v = (tt ? acc2_1[nt][r] : acc2_0[nt][r]) + b2[nt * 16 + l15];
            if (tt) pacc1[nt][r] += wv_ * v; else pacc0[nt][r] += wv_ * v;
          }
        }
    }
  }
  // private output
#pragma unroll
  for (int tt = 0; tt < 2; ++tt)
#pragma unroll
    for (int r = 0; r < 4; ++r) {
      int token = tb + tt * 16 + l4 * 4 + r;
#pragma unroll
      for (int nt = 0; nt < 8; ++nt)
        out[4194304 + (size_t)token * 128 + nt * 16 + l15] =
            tt ? pacc1[nt][r] : pacc0[nt][r];
    }
}

// ============== aux scalar ==============
__global__ void aux_kernel(const float* __restrict__ usage, float* __restrict__ out) {
  if (threadIdx.x == 0 && blockIdx.x == 0) {
    float a = 0.f;
    for (int e = 0; e < 8; ++e) {
      float u = usage[e] * (1.0f / 32768.0f);
      a += 0.125f * (logf(0.125f) - logf(u + 1e-10f));
    }
    out[8388608] = a * 0.125f;
  }
}

extern "C" void kernel_launch(void* const* d_in, const int* in_sizes, int n_in,
                              void* d_out, int out_size, void* d_ws, size_t ws_size,
                              hipStream_t stream) {
  (void)in_sizes; (void)n_in; (void)out_size; (void)ws_size;
  const float* x    = (const float*)d_in[0];
  const int*   mod  = (const int*)d_in[1];
  const float* A_W1 = (const float*)d_in[2];
  const float* A_b1 = (const float*)d_in[3];
  const float* A_W2 = (const float*)d_in[4];
  const float* A_b2 = (const float*)d_in[5];
  const float* B_W1 = (const float*)d_in[6];
  const float* B_b1 = (const float*)d_in[7];
  const float* B_g  = (const float*)d_in[8];
  const float* B_be = (const float*)d_in[9];
  const float* B_W2 = (const float*)d_in[10];
  const float* B_b2 = (const float*)d_in[11];
  const float* C_cw = (const float*)d_in[12];
  const float* C_cb = (const float*)d_in[13];
  const float* C_W  = (const float*)d_in[14];
  const float* C_b  = (const float*)d_in[15];
  const float* D_W1 = (const float*)d_in[16];
  const float* D_b1 = (const float*)d_in[17];
  const float* D_g  = (const float*)d_in[18];
  const float* D_be = (const float*)d_in[19];
  const float* D_W2 = (const float*)d_in[20];
  const float* D_b2 = (const float*)d_in[21];
  const float* S_W1 = (const float*)d_in[22];
  const float* S_b1 = (const float*)d_in[23];
  const float* S_g  = (const float*)d_in[24];
  const float* S_be = (const float*)d_in[25];
  const float* S_W2 = (const float*)d_in[26];
  const float* S_b2 = (const float*)d_in[27];
  const float* G_W1 = (const float*)d_in[28];
  const float* G_b1 = (const float*)d_in[29];
  const float* G_W2 = (const float*)d_in[30];
  const float* G_b2 = (const float*)d_in[31];

  char* ws = (char*)d_ws;
  unsigned short* W1cat = (unsigned short*)(ws + OFF_W1CAT);
  unsigned short* W2cat = (unsigned short*)(ws + OFF_W2CAT);
  float* W1T    = (float*)(ws + OFF_W1T);
  float* b1cat  = (float*)(ws + OFF_B1);
  float* b2cat  = (float*)(ws + OFF_B2);
  float* lng    = (float*)(ws + OFF_LNG);
  float* lnb    = (float*)(ws + OFF_LNB);
  float* bsc    = (float*)(ws + OFF_BSC);
  float* bbi    = (float*)(ws + OFF_BBI);
  float* usage  = (float*)(ws + OFF_USAGE);
  float* w8full = (float*)(ws + OFF_W8);
  float* out    = (float*)d_out;

  prep_kernel<<<1742, 256, 0, stream>>>(A_W1, A_b1, A_W2, A_b2, B_W1, B_b1, B_g, B_be,
      B_W2, B_b2, C_cw, C_cb, C_W, C_b, D_W1, D_b1, D_g, D_be, D_W2, D_b2,
      S_W1, S_b1, S_g, S_be, S_W2, S_b2, G_W1,
      W1cat, W2cat, W1T, b1cat, b2cat, lng, lnb, bsc, bbi, usage);
  prep2_kernel<<<4, 256, 0, stream>>>(C_cw, C_cb, C_W, b1cat);
  gate_np_kernel<<<512, 512, 0, stream>>>(x, mod, W1T, G_b1, G_W2, G_b2,
      w8full, usage);
  moe_kernel<<<512, 128, 0, stream>>>(x, W1cat, W2cat, b1cat, b2cat, lng, lnb,
      bsc, bbi, w8full, out);
  aux_kernel<<<1, 64, 0, stream>>>(usage, out);
}

// Round 8
// 336.977 us; speedup vs baseline: 1.9206x; 1.1752x over previous
//
#include <hip/hip_runtime.h>
#include <hip/hip_bf16.h>
#include <math.h>

typedef __attribute__((ext_vector_type(8))) short short8;      // 8 bf16 (4 VGPRs)
typedef __attribute__((ext_vector_type(4))) float f32x4;       // MFMA acc
typedef __attribute__((ext_vector_type(4))) unsigned short us4;

#define MFMA16(a,b,c) __builtin_amdgcn_mfma_f32_16x16x32_bf16((a),(b),(c),0,0,0)

// ---------------- workspace layout (bytes) ----------------
// W1cat: bf16 fragment-ordered [9][ks=8][nt=8][lane=64][j=8]
// W2cat: bf16 fragment-ordered [7][ks=4][nt=8][lane=64][j=8]
#define OFF_W1CAT   0u
#define OFF_W2CAT   589824u
#define OFF_B1      950272u    // f32 [9][128]
#define OFF_B2      954880u    // f32 [7][128]
#define OFF_LNG     958464u    // f32 [3][128] (D0,D1,S gains)
#define OFF_LNB     960000u    // f32 [3][128]
#define OFF_BSC     961536u    // f32 [2][128] B_g
#define OFF_BBI     962560u    // f32 [2][128] B_be
#define OFF_USAGE   963584u    // f32 [8]
#define OFF_W8      963712u    // f32 [32768][8]
#define OFF_W1T     2012288u   // f32 [257][128]  gate W1 transposed

__device__ __forceinline__ unsigned short f2bf(float f) {
  union { float f; unsigned u; } v; v.f = f;
  return (unsigned short)((v.u + 0x7fffu + ((v.u >> 16) & 1u)) >> 16);
}
// ---- fast activations (v_exp/v_rcp based; |err| << bf16 quantization) ----
__device__ __forceinline__ float frcp(float x) { return __builtin_amdgcn_rcpf(x); }
__device__ __forceinline__ float ftanh(float x) {
  float ax = fabsf(x);
  float t = __expf(-2.f * ax);
  float r = (1.f - t) * frcp(1.f + t);
  return copysignf(r, x);
}
__device__ __forceinline__ float fsilu(float x) {
  return x * frcp(1.f + __expf(-x));
}
__device__ __forceinline__ float fgelu(float x) {   // exact-erf form, A&S 7.1.26
  float ax = fabsf(x) * 0.70710678118654752f;
  float t = frcp(fmaf(0.3275911f, ax, 1.f));
  float p = fmaf(t, 1.061405429f, -1.453152027f);
  p = fmaf(t, p, 1.421413741f);
  p = fmaf(t, p, -0.284496736f);
  p = fmaf(t, p, 0.254829592f);
  p *= t;
  float erfv = copysignf(fmaf(-p, __expf(-ax * ax), 1.f), x);
  return 0.5f * x * (1.f + erfv);
}

// ============== prep: pack weights (fragment-ordered), fold conv ==============
__global__ __launch_bounds__(256) void prep_kernel(
    const float* __restrict__ A_W1, const float* __restrict__ A_b1,
    const float* __restrict__ A_W2, const float* __restrict__ A_b2,
    const float* __restrict__ B_W1, const float* __restrict__ B_b1,
    const float* __restrict__ B_g,  const float* __restrict__ B_be,
    const float* __restrict__ B_W2, const float* __restrict__ B_b2,
    const float* __restrict__ C_cw, const float* __restrict__ C_cb,
    const float* __restrict__ C_W,  const float* __restrict__ C_b,
    const float* __restrict__ D_W1, const float* __restrict__ D_b1,
    const float* __restrict__ D_g,  const float* __restrict__ D_be,
    const float* __restrict__ D_W2, const float* __restrict__ D_b2,
    const float* __restrict__ S_W1, const float* __restrict__ S_b1,
    const float* __restrict__ S_g,  const float* __restrict__ S_be,
    const float* __restrict__ S_W2, const float* __restrict__ S_b2,
    const float* __restrict__ G_W1,
    unsigned short* __restrict__ W1cat, unsigned short* __restrict__ W2cat,
    float* __restrict__ W1T,
    float* __restrict__ b1cat, float* __restrict__ b2cat,
    float* __restrict__ lng, float* __restrict__ lnb,
    float* __restrict__ bsc, float* __restrict__ bbi,
    float* __restrict__ usage)
{
  int tid = blockIdx.x * 256 + threadIdx.x;
  if (tid < 294912) {                       // W1cat, fragment order
    int g = tid >> 15, rem = tid & 32767;
    int j = rem & 7, lane = (rem >> 3) & 63, nt = (rem >> 9) & 7, ks = rem >> 12;
    int p = nt * 16 + (lane & 15);
    int k = ks * 32 + (lane >> 4) * 8 + j;
    int src = p * 256 + k;
    float v;
    if (g < 2)      v = A_W1[g * 32768 + src];
    else if (g < 4) v = B_W1[(g - 2) * 32768 + src];
    else if (g < 6) {                       // Weff = conv folded into C_W
      int e = g - 4;
      v = 0.f;
      for (int c = 0; c < 4; ++c)
        for (int jj = 0; jj < 3; ++jj) {
          int h = k + 1 - jj;
          if (h >= 0 && h < 256)
            v += C_cw[e*12 + c*3 + jj] * C_W[e*131072 + p*1024 + c*256 + h];
        }
    }
    else if (g < 8) v = D_W1[(g - 6) * 32768 + src];
    else            v = S_W1[src];
    W1cat[tid] = f2bf(v);
    return;
  }
  tid -= 294912;
  if (tid < 114688) {                       // W2cat, fragment order
    int g = tid >> 14, rem = tid & 16383;
    int j = rem & 7, lane = (rem >> 3) & 63, nt = (rem >> 9) & 7, ks = rem >> 12;
    int p = nt * 16 + (lane & 15);
    int k = ks * 32 + (lane >> 4) * 8 + j;
    int src = p * 128 + k;
    float v;
    if (g < 2)      v = A_W2[g * 16384 + src];
    else if (g < 4) v = B_W2[(g - 2) * 16384 + src];
    else if (g < 6) v = D_W2[(g - 4) * 16384 + src];
    else            v = S_W2[src];
    W2cat[tid] = f2bf(v);
    return;
  }
  tid -= 114688;
  if (tid < 32896) {                        // W1T[k][o] = G_W1[o][k]
    int k = tid / 128, o = tid % 128;
    W1T[tid] = G_W1[o * 257 + k];
    return;
  }
  tid -= 32896;
  if (tid < 1152) {                         // b1cat (C fold added by prep2)
    int g = tid / 128, p = tid % 128;
    float v;
    if (g < 2)      v = A_b1[tid];
    else if (g < 4) v = B_b1[p + (g - 2) * 128];
    else if (g < 6) v = C_b[(g - 4) * 128 + p];
    else if (g < 8) v = D_b1[p + (g - 6) * 128];
    else            v = S_b1[p];
    b1cat[tid] = v;
    return;
  }
  tid -= 1152;
  if (tid < 896) {                          // b2cat
    int g = tid / 128, p = tid % 128;
    float v;
    if (g < 2)      v = A_b2[tid];
    else if (g < 4) v = B_b2[p + (g - 2) * 128];
    else if (g < 6) v = D_b2[p + (g - 4) * 128];
    else            v = S_b2[p];
    b2cat[tid] = v;
    return;
  }
  tid -= 896;
  if (tid < 768) {                          // LN gains/biases (D0,D1,S)
    if (tid < 384) {
      int j = tid / 128, p = tid % 128;
      lng[tid] = (j < 2) ? D_g[tid] : S_g[p];
    } else {
      int q = tid - 384; int j = q / 128, p = q % 128;
      lnb[q] = (j < 2) ? D_be[q] : S_be[p];
    }
    return;
  }
  tid -= 768;
  if (tid < 512) {                          // B scale/shift
    if (tid < 256) bsc[tid] = B_g[tid];
    else           bbi[tid - 256] = B_be[tid - 256];
    return;
  }
  tid -= 512;
  if (tid < 8) usage[tid] = 0.f;
}

// prep2: parallel conv-bias fold
__global__ __launch_bounds__(256) void prep2_kernel(
    const float* __restrict__ C_cw_unused, const float* __restrict__ C_cb,
    const float* __restrict__ C_W, float* __restrict__ b1cat)
{
  int tid = blockIdx.x * 256 + threadIdx.x;   // 1024 threads: (e,p,c)
  int e = tid >> 9, rem = tid & 511;
  int p = rem >> 2, c = rem & 3;
  const float4* row = (const float4*)(C_W + e*131072 + p*1024 + c*256);
  float s = 0.f;
  for (int q = 0; q < 64; ++q) {
    float4 v = row[q];
    s += v.x + v.y + v.z + v.w;
  }
  atomicAdd(&b1cat[(4 + e) * 128 + p], C_cb[e * 4 + c] * s);
}

// ============== gate v3: token-on-lane, o-chains, exact np FMA order ==============
__global__ __launch_bounds__(512) void gate_np_kernel(
    const float* __restrict__ x, const int* __restrict__ modality,
    const float* __restrict__ W1T, const float* __restrict__ G_b1,
    const float* __restrict__ G_W2, const float* __restrict__ G_b2,
    float* __restrict__ w8full, float* __restrict__ usage)
{
  __shared__ unsigned char Ubuf[33024];     // xs [128][64] f32 (32KB) / ghs [64][129]
  __shared__ float ws2[8][132];
  __shared__ float lgs[64][9];
  float* xs  = (float*)Ubuf;
  float* ghs = (float*)Ubuf;
  const int tid = threadIdx.x;
  const int wv = __builtin_amdgcn_readfirstlane(tid >> 6);
  const int lane = tid & 63;
  const int tb = blockIdx.x * 64;
  const int o0 = wv * 16;
  const int t = lane;

  for (int i = tid; i < 1024; i += 512) ws2[i >> 7][i & 127] = G_W2[i];

  float acc[16];
#pragma unroll
  for (int j = 0; j < 16; ++j) acc[j] = 0.f;

  for (int p = 0; p < 2; ++p) {
    __syncthreads();                        // previous phase fully consumed
#pragma unroll
    for (int it = 0; it < 4; ++it) {
      int f = it * 512 + tid;               // float4 index in [64 rows][32 f4]
      int tt = f >> 5, c4 = f & 31;
      int kk = c4 * 4;
      const float4 v = *(const float4*)(x + (size_t)(tb + tt) * 256 + p * 128 + kk);
      int col = tt ^ (((kk >> 4) & 7) << 3);
      xs[(kk + 0) * 64 + col] = v.x;
      xs[(kk + 1) * 64 + col] = v.y;
      xs[(kk + 2) * 64 + col] = v.z;
      xs[(kk + 3) * 64 + col] = v.w;
    }
    __syncthreads();
    const float* wbase = W1T + (size_t)(p * 128) * 128 + o0;
    for (int kk = 0; kk < 128; ++kk) {
      float xv = xs[kk * 64 + (t ^ (((kk >> 4) & 7) << 3))];
      const float* wk = wbase + (size_t)kk * 128;
#pragma unroll
      for (int j = 0; j < 16; ++j)
        acc[j] = fmaf(xv, wk[j], acc[j]);   // exact sequential-k chain
    }
  }
  {
    float xv = (float)modality[tb + t];     // k = 256 (mod column)
    const float* wk = W1T + (size_t)256 * 128 + o0;
#pragma unroll
    for (int j = 0; j < 16; ++j)
      acc[j] = fmaf(xv, wk[j], acc[j]);
  }
  __syncthreads();                          // xs dead -> reuse as ghs
#pragma unroll
  for (int j = 0; j < 16; ++j)
    ghs[t * 129 + o0 + j] = (float)tanh((double)(acc[j] + G_b1[o0 + j]));
  __syncthreads();

  {
    int t2 = tid >> 3, e2 = tid & 7;
    float lg = 0.f;
    for (int o2 = 0; o2 < 128; ++o2)
      lg = fmaf(ghs[t2 * 129 + o2], ws2[e2][o2], lg);
    float s = (lg + G_b2[e2]) / 0.7f;       // f32 div
    lgs[t2][e2] = fminf(fmaxf(s, -10.f), 10.f);
  }
  __syncthreads();

  if (wv == 0) {                            // 64 tokens on 64 lanes
    int token = tb + lane;
    float v[8];
#pragma unroll
    for (int e = 0; e < 8; ++e) v[e] = lgs[lane][e];
    float tv[4]; int ti[4]; unsigned msk = 0;
    for (int kk = 0; kk < 4; ++kk) {        // ties -> lowest idx
      float best = -1e30f; int bi = 0;
      for (int e = 0; e < 8; ++e)
        if (!((msk >> e) & 1u) && v[e] > best) { best = v[e]; bi = e; }
      tv[kk] = best; ti[kk] = bi; msk |= 1u << bi;
    }
    float mx = tv[0], den = 0.f, wk4[4];
#pragma unroll
    for (int kk = 0; kk < 4; ++kk) { wk4[kk] = expf(tv[kk] - mx); den += wk4[kk]; }
#pragma unroll
    for (int e = 0; e < 8; ++e) {
      float val = 0.f;
#pragma unroll
      for (int kk = 0; kk < 4; ++kk) if (ti[kk] == e) val = wk4[kk] / den;
      w8full[(size_t)token * 8 + e] = val;
    }
    float uw[8];
    float dall = 0.f, pe[8];
#pragma unroll
    for (int e = 0; e < 8; ++e) { pe[e] = expf(v[e] - mx); dall += pe[e]; }
#pragma unroll
    for (int e = 0; e < 8; ++e) uw[e] = pe[e] / dall;
    for (int m = 1; m <= 32; m <<= 1)
#pragma unroll
      for (int e = 0; e < 8; ++e) uw[e] += __shfl_xor(uw[e], m);
    if (lane == 0)
      for (int e = 0; e < 8; ++e) atomicAdd(usage + e, uw[e]);
  }
}

// ============== moe v6: group-per-wave + B-prefetch + fast epilogue ==============
__global__ __launch_bounds__(512, 4) void moe_kernel(
    const float* __restrict__ x,
    const unsigned short* __restrict__ W1cat, const unsigned short* __restrict__ W2cat,
    const float* __restrict__ b1cat, const float* __restrict__ b2cat,
    const float* __restrict__ lng, const float* __restrict__ lnb,
    const float* __restrict__ bsc, const float* __restrict__ bbi,
    const float* __restrict__ w8full, float* __restrict__ out)
{
  // LDS: XS 8192 | HS 8*4096 | HS_S 4096 | pacc 8192 | partS 1024
  __shared__ unsigned char smem[54272];
  unsigned char* XS   = smem;
  unsigned char* HSb  = smem + 8192;
  unsigned char* HS_S = smem + 8192 + 32768;
  float* pacc_f = (float*)(smem + 8192 + 32768 + 4096);
  float* partS  = (float*)(smem + 8192 + 32768 + 4096 + 8192);  // [2][8][16]

  const int wv = threadIdx.x >> 6, lane = threadIdx.x & 63;
  const int l15 = lane & 15, l4 = lane >> 4;
  const int tb = blockIdx.x * 16;
  const int g = wv;
  const short8* W1f = (const short8*)W1cat;   // [(g*8+ks)*8+nt][64] frags
  const short8* W2f = (const short8*)W2cat;   // [(g2*4+ks)*8+nt][64] frags

  for (int i = threadIdx.x; i < 2048; i += 512) pacc_f[i] = 0.f;
  if (wv < 4) {
#pragma unroll
    for (int i = 0; i < 4; ++i) {
      int r = wv * 4 + i;
      const float4 v = *(const float4*)(x + (size_t)(tb + r) * 256 + lane * 4);
      float vv[4] = {v.x, v.y, v.z, v.w};
      us4 hi;
#pragma unroll
      for (int j = 0; j < 4; ++j) hi[j] = f2bf(vv[j]);
      int addr = r * 512 + ((((lane >> 1) ^ (r & 7)) << 4) | ((lane & 1) << 3));
      *(us4*)(XS + addr) = hi;
    }
  }
  __syncthreads();

  f32x4 zero = {0.f, 0.f, 0.f, 0.f};
  const float RS = 1.0f / sqrtf(1.0f + 1e-5f);
  unsigned char* HS = HSb + wv * 4096;

  // ---- this wave's expert group g: GEMM1 with 1-deep B prefetch ----
  {
    const short8* bg = W1f + (size_t)(g * 64) * 64 + lane;   // + ks*512 + nt*64
    f32x4 acc[8];
    short8 bA[8], bB[8];
#pragma unroll
    for (int nt = 0; nt < 8; ++nt) { acc[nt] = zero; bA[nt] = bg[nt * 64]; }
#pragma unroll
    for (int ks = 0; ks < 8; ++ks) {
      int ar = l15 * 512 + ((((ks * 4 + l4) ^ (l15 & 7)) << 4));
      short8 a = *(const short8*)(XS + ar);
      if (ks < 7) {
#pragma unroll
        for (int nt = 0; nt < 8; ++nt) bB[nt] = bg[(ks + 1) * 512 + nt * 64];
      }
#pragma unroll
      for (int nt = 0; nt < 8; ++nt) acc[nt] = MFMA16(a, bA[nt], acc[nt]);
      if (ks < 7) {
#pragma unroll
        for (int nt = 0; nt < 8; ++nt) bA[nt] = bB[nt];
      }
    }
    const float* b1 = b1cat + g * 128;
    const int type = (g < 2) ? 0 : (g < 4) ? 1 : (g < 6) ? 2 : 3;

    if (type == 2) {                        // C: fast gelu -> weighted pacc
#pragma unroll
      for (int r = 0; r < 4; ++r) {
        float wv_ = w8full[(size_t)(tb + l4 * 4 + r) * 8 + g];
#pragma unroll
        for (int nt = 0; nt < 8; ++nt) {
          float h = fgelu(acc[nt][r] + b1[nt * 16 + l15]);
          atomicAdd(&pacc_f[(l4 * 4 + r) * 128 + nt * 16 + l15], wv_ * h);
        }
      }
    } else {
#pragma unroll
      for (int r = 0; r < 4; ++r) {
#pragma unroll
        for (int nt = 0; nt < 8; ++nt) {
          float h = acc[nt][r] + b1[nt * 16 + l15];
          if (type == 0)      h = fmaxf(h, 0.f);
          else if (type == 1) {
            int col = (g - 2) * 128 + nt * 16 + l15;
            h = ftanh(h) * RS * bsc[col] + bbi[col];
          }
          else                h = fsilu(h);             // silu (D)
          acc[nt][r] = h;
        }
      }
      if (type == 3) {                      // D layernorm (in-wave shuffles)
        int li = g - 6;
#pragma unroll
        for (int r = 0; r < 4; ++r) {
          float s1 = 0.f, s2 = 0.f;
#pragma unroll
          for (int nt = 0; nt < 8; ++nt) { float h = acc[nt][r]; s1 += h; s2 += h * h; }
          for (int m = 1; m <= 8; m <<= 1) { s1 += __shfl_xor(s1, m); s2 += __shfl_xor(s2, m); }
          float mu = s1 * (1.f / 128.f);
          float var = s2 * (1.f / 128.f) - mu * mu;
          float sc = __builtin_amdgcn_rsqf(var + 1e-5f);
#pragma unroll
          for (int nt = 0; nt < 8; ++nt) {
            int col = nt * 16 + l15;
            acc[nt][r] = (acc[nt][r] - mu) * sc * lng[li * 128 + col] + lnb[li * 128 + col];
          }
        }
      }
      // write h tile (bf16, swizzled, per-wave region)
#pragma unroll
      for (int r = 0; r < 4; ++r) {
        int row = l4 * 4 + r;
#pragma unroll
        for (int nt = 0; nt < 8; ++nt) {
          int bytecol = (nt * 16 + l15) * 2;
          int addr = row * 256 + ((((bytecol >> 4) ^ (row & 7)) << 4) | (bytecol & 15));
          *(unsigned short*)(HS + addr) = f2bf(acc[nt][r]);
        }
      }
      // GEMM2 with 1-deep B prefetch
      const int g2 = (g < 4) ? g : (g - 2);
      const short8* bg2 = W2f + (size_t)(g2 * 32) * 64 + lane;   // + ks*512 + nt*64
      f32x4 acc2[8];
      short8 cA[8], cB[8];
#pragma unroll
      for (int nt = 0; nt < 8; ++nt) { acc2[nt] = zero; cA[nt] = bg2[nt * 64]; }
#pragma unroll
      for (int ks = 0; ks < 4; ++ks) {
        int ar = l15 * 256 + ((((ks * 4 + l4) ^ (l15 & 7)) << 4));
        short8 a = *(const short8*)(HS + ar);
        if (ks < 3) {
#pragma unroll
          for (int nt = 0; nt < 8; ++nt) cB[nt] = bg2[(ks + 1) * 512 + nt * 64];
        }
#pragma unroll
        for (int nt = 0; nt < 8; ++nt) acc2[nt] = MFMA16(a, cA[nt], acc2[nt]);
        if (ks < 3) {
#pragma unroll
          for (int nt = 0; nt < 8; ++nt) cA[nt] = cB[nt];
        }
      }
      const float* b2 = b2cat + g2 * 128;
#pragma unroll
      for (int r = 0; r < 4; ++r) {
        float wv_ = w8full[(size_t)(tb + l4 * 4 + r) * 8 + g];
#pragma unroll
        for (int nt = 0; nt < 8; ++nt)
          atomicAdd(&pacc_f[(l4 * 4 + r) * 128 + nt * 16 + l15],
                    wv_ * (acc2[nt][r] + b2[nt * 16 + l15]));
      }
    }
  }

  // ---- S network, split by 16-col block: this wave handles nt = wv ----
  {
    short8 bS[8];
#pragma unroll
    for (int ks = 0; ks < 8; ++ks)
      bS[ks] = W1f[((size_t)(64 + ks) * 8 + wv) * 64 + lane];
    f32x4 accS = zero;
#pragma unroll
    for (int ks = 0; ks < 8; ++ks) {
      int ar = l15 * 512 + ((((ks * 4 + l4) ^ (l15 & 7)) << 4));
      short8 a = *(const short8*)(XS + ar);
      accS = MFMA16(a, bS[ks], accS);
    }
    float bS1 = b1cat[8 * 128 + wv * 16 + l15];
#pragma unroll
    for (int r = 0; r < 4; ++r) accS[r] = fmaxf(accS[r] + bS1, 0.f);
#pragma unroll
    for (int r = 0; r < 4; ++r) {
      float s1 = accS[r], s2 = accS[r] * accS[r];
      for (int m = 1; m <= 8; m <<= 1) { s1 += __shfl_xor(s1, m); s2 += __shfl_xor(s2, m); }
      if (l15 == 0) {
        partS[wv * 16 + l4 * 4 + r] = s1;
        partS[128 + wv * 16 + l4 * 4 + r] = s2;
      }
    }
    __syncthreads();
#pragma unroll
    for (int r = 0; r < 4; ++r) {
      int row = l4 * 4 + r;
      float s1 = 0.f, s2 = 0.f;
#pragma unroll
      for (int q = 0; q < 8; ++q) { s1 += partS[q * 16 + row]; s2 += partS[128 + q * 16 + row]; }
      float mu = s1 * (1.f / 128.f);
      float var = s2 * (1.f / 128.f) - mu * mu;
      float sc = __builtin_amdgcn_rsqf(var + 1e-5f);
      int col = wv * 16 + l15;
      float hn = (accS[r] - mu) * sc * lng[2 * 128 + col] + lnb[2 * 128 + col];
      int bytecol = col * 2;
      int addr = row * 256 + ((((bytecol >> 4) ^ (row & 7)) << 4) | (bytecol & 15));
      *(unsigned short*)(HS_S + addr) = f2bf(hn);
    }
    __syncthreads();
    short8 cS[4];
#pragma unroll
    for (int ks = 0; ks < 4; ++ks)
      cS[ks] = W2f[((size_t)(24 + ks) * 8 + wv) * 64 + lane];
    f32x4 acc2S = zero;
#pragma unroll
    for (int ks = 0; ks < 4; ++ks) {
      int ar = l15 * 256 + ((((ks * 4 + l4) ^ (l15 & 7)) << 4));
      short8 a = *(const short8*)(HS_S + ar);
      acc2S = MFMA16(a, cS[ks], acc2S);
    }
    float b2S = b2cat[6 * 128 + wv * 16 + l15];
#pragma unroll
    for (int r = 0; r < 4; ++r)
      out[(size_t)(tb + l4 * 4 + r) * 128 + wv * 16 + l15] = acc2S[r] + b2S;
  }

  __syncthreads();
  for (int i = threadIdx.x; i < 2048; i += 512)
    out[4194304 + (size_t)tb * 128 + i] = pacc_f[i];
}

// ============== aux scalar ==============
__global__ void aux_kernel(const float* __restrict__ usage, float* __restrict__ out) {
  if (threadIdx.x == 0 && blockIdx.x == 0) {
    float a = 0.f;
    for (int e = 0; e < 8; ++e) {
      float u = usage[e] * (1.0f / 32768.0f);
      a += 0.125f * (logf(0.125f) - logf(u + 1e-10f));
    }
    out[8388608] = a * 0.125f;
  }
}

extern "C" void kernel_launch(void* const* d_in, const int* in_sizes, int n_in,
                              void* d_out, int out_size, void* d_ws, size_t ws_size,
                              hipStream_t stream) {
  (void)in_sizes; (void)n_in; (void)out_size; (void)ws_size;
  const float* x    = (const float*)d_in[0];
  const int*   mod  = (const int*)d_in[1];
  const float* A_W1 = (const float*)d_in[2];
  const float* A_b1 = (const float*)d_in[3];
  const float* A_W2 = (const float*)d_in[4];
  const float* A_b2 = (const float*)d_in[5];
  const float* B_W1 = (const float*)d_in[6];
  const float* B_b1 = (const float*)d_in[7];
  const float* B_g  = (const float*)d_in[8];
  const float* B_be = (const float*)d_in[9];
  const float* B_W2 = (const float*)d_in[10];
  const float* B_b2 = (const float*)d_in[11];
  const float* C_cw = (const float*)d_in[12];
  const float* C_cb = (const float*)d_in[13];
  const float* C_W  = (const float*)d_in[14];
  const float* C_b  = (const float*)d_in[15];
  const float* D_W1 = (const float*)d_in[16];
  const float* D_b1 = (const float*)d_in[17];
  const float* D_g  = (const float*)d_in[18];
  const float* D_be = (const float*)d_in[19];
  const float* D_W2 = (const float*)d_in[20];
  const float* D_b2 = (const float*)d_in[21];
  const float* S_W1 = (const float*)d_in[22];
  const float* S_b1 = (const float*)d_in[23];
  const float* S_g  = (const float*)d_in[24];
  const float* S_be = (const float*)d_in[25];
  const float* S_W2 = (const float*)d_in[26];
  const float* S_b2 = (const float*)d_in[27];
  const float* G_W1 = (const float*)d_in[28];
  const float* G_b1 = (const float*)d_in[29];
  const float* G_W2 = (const float*)d_in[30];
  const float* G_b2 = (const float*)d_in[31];

  char* ws = (char*)d_ws;
  unsigned short* W1cat = (unsigned short*)(ws + OFF_W1CAT);
  unsigned short* W2cat = (unsigned short*)(ws + OFF_W2CAT);
  float* W1T    = (float*)(ws + OFF_W1T);
  float* b1cat  = (float*)(ws + OFF_B1);
  float* b2cat  = (float*)(ws + OFF_B2);
  float* lng    = (float*)(ws + OFF_LNG);
  float* lnb    = (float*)(ws + OFF_LNB);
  float* bsc    = (float*)(ws + OFF_BSC);
  float* bbi    = (float*)(ws + OFF_BBI);
  float* usage  = (float*)(ws + OFF_USAGE);
  float* w8full = (float*)(ws + OFF_W8);
  float* out    = (float*)d_out;

  prep_kernel<<<1742, 256, 0, stream>>>(A_W1, A_b1, A_W2, A_b2, B_W1, B_b1, B_g, B_be,
      B_W2, B_b2, C_cw, C_cb, C_W, C_b, D_W1, D_b1, D_g, D_be, D_W2, D_b2,
      S_W1, S_b1, S_g, S_be, S_W2, S_b2, G_W1,
      W1cat, W2cat, W1T, b1cat, b2cat, lng, lnb, bsc, bbi, usage);
  prep2_kernel<<<4, 256, 0, stream>>>(C_cw, C_cb, C_W, b1cat);
  gate_np_kernel<<<512, 512, 0, stream>>>(x, mod, W1T, G_b1, G_W2, G_b2,
      w8full, usage);
  moe_kernel<<<2048, 512, 0, stream>>>(x, W1cat, W2cat, b1cat, b2cat, lng, lnb,
      bsc, bbi, w8full, out);
  aux_kernel<<<1, 64, 0, stream>>>(usage, out);
}